// Round 1
// baseline (2591.026 us; speedup 1.0000x reference)
//
#include <hip/hip_runtime.h>
#include <hip/hip_bf16.h>
#include <math.h>

#define MD 1024          // model dim
#define NH 16            // heads
#define HD 64            // head dim
#define BATCH 4
#define SEQ 2048

// ---------------------------------------------------------------------------
// GEMM: C[M,N] = A[M,K] @ W[K,N] + bias[N] (+ residual[M,N] if non-null)
// 64x64 tile, BK=16, 256 threads, 4x4 micro-tile per thread, fp32.
// ---------------------------------------------------------------------------
__global__ __launch_bounds__(256)
void gemm_bias_kernel(const float* __restrict__ A, const float* __restrict__ W,
                      const float* __restrict__ bias, const float* __restrict__ residual,
                      float* __restrict__ C, int K, int N)
{
    __shared__ float Ast[16][64];   // transposed A tile: [k][m]
    __shared__ float Ws [16][64];   // [k][n]

    const int tid = threadIdx.x;
    const int tx  = tid & 15;       // 0..15 -> n group
    const int ty  = tid >> 4;       // 0..15 -> m group
    const int brow = blockIdx.y * 64;
    const int bcol = blockIdx.x * 64;

    // staging indices
    const int lrow = tid >> 2;          // 0..63 (A row in tile)
    const int lk   = (tid & 3) * 4;     // 0,4,8,12 (A k quad)
    const int wrow = tid >> 4;          // 0..15 (W k row)
    const int wcol = (tid & 15) * 4;    // W n quad

    float acc[4][4] = {};

    for (int k0 = 0; k0 < K; k0 += 16) {
        float4 a = *(const float4*)(A + (size_t)(brow + lrow) * K + k0 + lk);
        float4 w = *(const float4*)(W + (size_t)(k0 + wrow) * N + bcol + wcol);
        __syncthreads();                 // prior iteration's LDS reads done
        Ast[lk + 0][lrow] = a.x;
        Ast[lk + 1][lrow] = a.y;
        Ast[lk + 2][lrow] = a.z;
        Ast[lk + 3][lrow] = a.w;
        *(float4*)&Ws[wrow][wcol] = w;
        __syncthreads();

        #pragma unroll
        for (int kk = 0; kk < 16; ++kk) {
            float4 a4 = *(const float4*)&Ast[kk][ty * 4];
            float4 w4 = *(const float4*)&Ws [kk][tx * 4];
            float ar[4] = {a4.x, a4.y, a4.z, a4.w};
            float wr[4] = {w4.x, w4.y, w4.z, w4.w};
            #pragma unroll
            for (int i = 0; i < 4; ++i)
                #pragma unroll
                for (int j = 0; j < 4; ++j)
                    acc[i][j] = fmaf(ar[i], wr[j], acc[i][j]);
        }
    }

    #pragma unroll
    for (int i = 0; i < 4; ++i) {
        const size_t row = (size_t)(brow + ty * 4 + i);
        const int col = bcol + tx * 4;
        float4 b4 = *(const float4*)(bias + col);
        float4 r;
        r.x = acc[i][0] + b4.x;
        r.y = acc[i][1] + b4.y;
        r.z = acc[i][2] + b4.z;
        r.w = acc[i][3] + b4.w;
        if (residual != nullptr) {
            float4 rs = *(const float4*)(residual + row * N + col);
            r.x += rs.x; r.y += rs.y; r.z += rs.z; r.w += rs.w;
        }
        *(float4*)(C + row * N + col) = r;
    }
}

// ---------------------------------------------------------------------------
// Flash-style attention, fp32.
// Grid: (SEQ/64, NH, BATCH). Block: 256 threads.
// Q,K,V laid out [B*S, NH*HD] (projection output). O same layout.
// Per block: 64 q-rows of one head; loop over 32 k-tiles of 64.
// ---------------------------------------------------------------------------
__global__ __launch_bounds__(256)
void attn_kernel(const float* __restrict__ Qp, const float* __restrict__ Kp,
                 const float* __restrict__ Vp, float* __restrict__ Op)
{
    __shared__ float Qt[64][68];   // [d][i], pre-scaled by 1/sqrt(HD)
    __shared__ float Kt[64][68];   // [d][j]
    __shared__ float Vs[64][64];   // [j][d]
    __shared__ float Pt[64][68];   // [j][i]

    const int tid = threadIdx.x;
    const int tx  = tid & 15;      // kcol / dcol group
    const int ty  = tid >> 4;      // qrow group
    const int qt = blockIdx.x;
    const int h  = blockIdx.y;
    const int b  = blockIdx.z;

    const int lr = tid >> 4;             // 0..15 (row within a 16-row stripe)
    const int lc = (tid & 15) * 4;       // col quad 0..60

    const size_t bh_off = ((size_t)b * SEQ) * MD + (size_t)h * HD;
    const size_t qbase  = bh_off + (size_t)qt * 64 * MD;

    // ---- stage Q transposed, scaled by 1/8 (= 1/sqrt(64), exact) ----
    #pragma unroll
    for (int it = 0; it < 4; ++it) {
        const int r = lr + it * 16;
        float4 q = *(const float4*)(Qp + qbase + (size_t)r * MD + lc);
        Qt[lc + 0][r] = q.x * 0.125f;
        Qt[lc + 1][r] = q.y * 0.125f;
        Qt[lc + 2][r] = q.z * 0.125f;
        Qt[lc + 3][r] = q.w * 0.125f;
    }

    float m[4], l[4], o[4][4];
    #pragma unroll
    for (int i = 0; i < 4; ++i) {
        m[i] = -INFINITY;
        l[i] = 0.0f;
        #pragma unroll
        for (int j = 0; j < 4; ++j) o[i][j] = 0.0f;
    }

    for (int kt = 0; kt < SEQ / 64; ++kt) {
        const size_t kbase = bh_off + (size_t)kt * 64 * MD;
        float4 kf[4], vf[4];
        #pragma unroll
        for (int it = 0; it < 4; ++it) {
            const int r = lr + it * 16;
            kf[it] = *(const float4*)(Kp + kbase + (size_t)r * MD + lc);
            vf[it] = *(const float4*)(Vp + kbase + (size_t)r * MD + lc);
        }
        __syncthreads();   // prior tile's LDS reads (Kt/Vs/Pt) complete
        #pragma unroll
        for (int it = 0; it < 4; ++it) {
            const int r = lr + it * 16;
            Kt[lc + 0][r] = kf[it].x;
            Kt[lc + 1][r] = kf[it].y;
            Kt[lc + 2][r] = kf[it].z;
            Kt[lc + 3][r] = kf[it].w;
            *(float4*)&Vs[r][lc] = vf[it];
        }
        __syncthreads();

        // ---- scores: S[i][j] = sum_d Qt[d][i] * Kt[d][j] ----
        float s[4][4] = {};
        #pragma unroll
        for (int d = 0; d < 64; ++d) {
            float4 q4 = *(const float4*)&Qt[d][ty * 4];
            float4 k4 = *(const float4*)&Kt[d][tx * 4];
            float qr[4] = {q4.x, q4.y, q4.z, q4.w};
            float kr[4] = {k4.x, k4.y, k4.z, k4.w};
            #pragma unroll
            for (int i = 0; i < 4; ++i)
                #pragma unroll
                for (int j = 0; j < 4; ++j)
                    s[i][j] = fmaf(qr[i], kr[j], s[i][j]);
        }

        // ---- online softmax (row reduce over 16 tx lanes) ----
        #pragma unroll
        for (int i = 0; i < 4; ++i) {
            float mx = fmaxf(fmaxf(s[i][0], s[i][1]), fmaxf(s[i][2], s[i][3]));
            mx = fmaxf(mx, __shfl_xor(mx, 1));
            mx = fmaxf(mx, __shfl_xor(mx, 2));
            mx = fmaxf(mx, __shfl_xor(mx, 4));
            mx = fmaxf(mx, __shfl_xor(mx, 8));
            const float mnew = fmaxf(m[i], mx);
            const float corr = __expf(m[i] - mnew);
            m[i] = mnew;
            float ps = 0.0f;
            #pragma unroll
            for (int j = 0; j < 4; ++j) {
                s[i][j] = __expf(s[i][j] - mnew);
                ps += s[i][j];
            }
            ps += __shfl_xor(ps, 1);
            ps += __shfl_xor(ps, 2);
            ps += __shfl_xor(ps, 4);
            ps += __shfl_xor(ps, 8);
            l[i] = l[i] * corr + ps;
            #pragma unroll
            for (int j = 0; j < 4; ++j) o[i][j] *= corr;
        }

        // ---- write P transposed: Pt[j][i], packed float4 along i ----
        #pragma unroll
        for (int kj = 0; kj < 4; ++kj) {
            float4 p = make_float4(s[0][kj], s[1][kj], s[2][kj], s[3][kj]);
            *(float4*)&Pt[tx * 4 + kj][ty * 4] = p;
        }
        __syncthreads();

        // ---- PV: o[i][dj] += sum_j P[i][j] * V[j][dj] ----
        #pragma unroll
        for (int j = 0; j < 64; ++j) {
            float4 p4 = *(const float4*)&Pt[j][ty * 4];
            float4 v4 = *(const float4*)&Vs[j][tx * 4];
            float pr[4] = {p4.x, p4.y, p4.z, p4.w};
            float vr[4] = {v4.x, v4.y, v4.z, v4.w};
            #pragma unroll
            for (int i = 0; i < 4; ++i)
                #pragma unroll
                for (int jj = 0; jj < 4; ++jj)
                    o[i][jj] = fmaf(pr[i], vr[jj], o[i][jj]);
        }
    }

    // ---- normalize + store ----
    #pragma unroll
    for (int i = 0; i < 4; ++i) {
        const float inv = 1.0f / l[i];
        float4 r = make_float4(o[i][0] * inv, o[i][1] * inv, o[i][2] * inv, o[i][3] * inv);
        *(float4*)(Op + qbase + (size_t)(ty * 4 + i) * MD + tx * 4) = r;
    }
}

// ---------------------------------------------------------------------------
// In-place LayerNorm over last dim (1024). One block per row, 256 threads.
// ---------------------------------------------------------------------------
__global__ __launch_bounds__(256)
void ln_kernel(float* __restrict__ X, const float* __restrict__ gamma,
               const float* __restrict__ beta)
{
    const int row = blockIdx.x;
    const int tid = threadIdx.x;
    float* px = X + (size_t)row * MD;
    float4 x = ((const float4*)px)[tid];
    float s  = x.x + x.y + x.z + x.w;
    float ss = fmaf(x.x, x.x, fmaf(x.y, x.y, fmaf(x.z, x.z, x.w * x.w)));
    #pragma unroll
    for (int off = 1; off < 64; off <<= 1) {
        s  += __shfl_xor(s,  off);
        ss += __shfl_xor(ss, off);
    }
    __shared__ float red[8];
    const int wid = tid >> 6;
    if ((tid & 63) == 0) { red[wid] = s; red[wid + 4] = ss; }
    __syncthreads();
    s  = red[0] + red[1] + red[2] + red[3];
    ss = red[4] + red[5] + red[6] + red[7];
    const float mu   = s * (1.0f / MD);
    const float var  = ss * (1.0f / MD) - mu * mu;
    const float rstd = rsqrtf(var + 1e-5f);
    float4 g  = ((const float4*)gamma)[tid];
    float4 be = ((const float4*)beta)[tid];
    float4 r;
    r.x = (x.x - mu) * rstd * g.x + be.x;
    r.y = (x.y - mu) * rstd * g.y + be.y;
    r.z = (x.z - mu) * rstd * g.z + be.z;
    r.w = (x.w - mu) * rstd * g.w + be.w;
    ((float4*)px)[tid] = r;
}

// ---------------------------------------------------------------------------
extern "C" void kernel_launch(void* const* d_in, const int* in_sizes, int n_in,
                              void* d_out, int out_size, void* d_ws, size_t ws_size,
                              hipStream_t stream)
{
    const float* query = (const float*)d_in[0];
    const float* key   = (const float*)d_in[1];
    const float* value = (const float*)d_in[2];
    const float* Wq = (const float*)d_in[3];
    const float* bq = (const float*)d_in[4];
    const float* Wk = (const float*)d_in[5];
    const float* bk = (const float*)d_in[6];
    const float* Wv = (const float*)d_in[7];
    const float* bv = (const float*)d_in[8];
    const float* Wo = (const float*)d_in[9];
    const float* bo = (const float*)d_in[10];
    const float* gamma = (const float*)d_in[11];
    const float* beta  = (const float*)d_in[12];
    float* out = (float*)d_out;

    const size_t NTOK = (size_t)BATCH * SEQ;          // 8192 rows
    float* qp = (float*)d_ws;                         // [NTOK][MD]
    float* kp = qp + NTOK * MD;
    float* vp = kp + NTOK * MD;
    float* ao = vp + NTOK * MD;

    dim3 blk(256);
    dim3 ggemm(MD / 64, NTOK / 64);                   // (16, 128)

    gemm_bias_kernel<<<ggemm, blk, 0, stream>>>(query, Wq, bq, nullptr, qp, MD, MD);
    gemm_bias_kernel<<<ggemm, blk, 0, stream>>>(key,   Wk, bk, nullptr, kp, MD, MD);
    gemm_bias_kernel<<<ggemm, blk, 0, stream>>>(value, Wv, bv, nullptr, vp, MD, MD);

    dim3 gattn(SEQ / 64, NH, BATCH);
    attn_kernel<<<gattn, blk, 0, stream>>>(qp, kp, vp, ao);

    // O-projection + bias + residual straight into d_out
    gemm_bias_kernel<<<ggemm, blk, 0, stream>>>(ao, Wo, bo, query, out, MD, MD);

    // LayerNorm in place on d_out
    ln_kernel<<<NTOK, blk, 0, stream>>>(out, gamma, beta);
}

// Round 2
// 359.819 us; speedup vs baseline: 7.2009x; 7.2009x over previous
//
#include <hip/hip_runtime.h>
#include <math.h>

#define MD 1024
#define NH 16
#define HD 64
#define BATCH 4
#define SEQ 2048

typedef __attribute__((ext_vector_type(8))) short short8;
typedef __attribute__((ext_vector_type(4))) short short4v;
typedef __attribute__((ext_vector_type(4))) float f32x4;

__device__ inline unsigned short f2b(float f) {
    unsigned u = __builtin_bit_cast(unsigned, f);
    unsigned r = (u + 0x7fffu + ((u >> 16) & 1u)) >> 16;
    return (unsigned short)r;
}
__device__ inline float b2f(unsigned short s) {
    return __builtin_bit_cast(float, ((unsigned)s) << 16);
}

// ---------------------------------------------------------------------------
// fp32 -> bf16 elementwise convert (activations)
// ---------------------------------------------------------------------------
__global__ __launch_bounds__(256)
void convbf(const float* __restrict__ x, unsigned short* __restrict__ y, int n)
{
    int i = (blockIdx.x * 256 + threadIdx.x) * 8;
    if (i >= n) return;
    f32x4 a = *(const f32x4*)(x + i);
    f32x4 b = *(const f32x4*)(x + i + 4);
    short8 o;
    o[0] = (short)f2b(a[0]); o[1] = (short)f2b(a[1]);
    o[2] = (short)f2b(a[2]); o[3] = (short)f2b(a[3]);
    o[4] = (short)f2b(b[0]); o[5] = (short)f2b(b[1]);
    o[6] = (short)f2b(b[2]); o[7] = (short)f2b(b[3]);
    *(short8*)(y + i) = o;
}

// ---------------------------------------------------------------------------
// W[K][N] fp32 -> WT[N][K] bf16 (transpose + convert), 64x64 tiles
// ---------------------------------------------------------------------------
__global__ __launch_bounds__(256)
void wtrans(const float* __restrict__ W, unsigned short* __restrict__ WT)
{
    __shared__ __attribute__((aligned(16))) float T[64][68];
    const int tid = threadIdx.x;
    const int nt = blockIdx.x, kt = blockIdx.y;
    #pragma unroll
    for (int i = 0; i < 4; ++i) {
        int u = tid + i * 256;         // 1024 float4 units
        int row = u >> 4, c4 = u & 15; // row = k-local
        f32x4 v = *(const f32x4*)(W + (size_t)(kt * 64 + row) * MD + nt * 64 + c4 * 4);
        *(f32x4*)&T[row][c4 * 4] = v;
    }
    __syncthreads();
    #pragma unroll
    for (int i = 0; i < 2; ++i) {
        int u = tid + i * 256;         // 512 short8 units
        int n = u >> 3, c16 = u & 7;
        short8 o;
        #pragma unroll
        for (int j = 0; j < 8; ++j) o[j] = (short)f2b(T[c16 * 8 + j][n]);
        *(short8*)(WT + (size_t)(nt * 64 + n) * MD + kt * 64 + c16 * 8) = o;
    }
}

// ---------------------------------------------------------------------------
// vp[B*S][MD] bf16 -> vt[bh][d][s] bf16 (per-head transpose), 64x64 tiles
// ---------------------------------------------------------------------------
__global__ __launch_bounds__(256)
void vtrans(const unsigned short* __restrict__ vp, unsigned short* __restrict__ vt)
{
    __shared__ __attribute__((aligned(16))) short T[64][72];
    const int tid = threadIdx.x;
    const int st = blockIdx.x, bh = blockIdx.y;
    const int b = bh >> 4, h = bh & 15;
    #pragma unroll
    for (int i = 0; i < 2; ++i) {
        int u = tid + i * 256;
        int row = u >> 3, c16 = u & 7;   // row = s-local
        short8 v = *(const short8*)(vp + ((size_t)b * SEQ + st * 64 + row) * MD + h * 64 + c16 * 8);
        *(short8*)&T[row][c16 * 8] = v;
    }
    __syncthreads();
    #pragma unroll
    for (int i = 0; i < 2; ++i) {
        int u = tid + i * 256;
        int d = u >> 3, c16 = u & 7;
        short8 o;
        #pragma unroll
        for (int j = 0; j < 8; ++j) o[j] = T[c16 * 8 + j][d];
        *(short8*)(vt + ((size_t)bh * 64 + d) * SEQ + st * 64 + c16 * 8) = o;
    }
}

// ---------------------------------------------------------------------------
// bf16 MFMA GEMM: C[M][1024] = A[M][1024] @ W + bias (+residual)
// A bf16 row-major, Bt = W^T bf16 [1024 n][1024 k] row-major.
// 128x128 tile, BK=64, 256 thr = 4 waves (2x2), each wave 64x64 (4x4 frags).
// ---------------------------------------------------------------------------
__global__ __launch_bounds__(256, 2)
void gemm_bf16(const unsigned short* __restrict__ A,
               const unsigned short* __restrict__ Bt,
               const float* __restrict__ bias,
               const float* __restrict__ residual,
               unsigned short* __restrict__ Cb,
               float* __restrict__ Cf)
{
    __shared__ __attribute__((aligned(16))) short As[128 * 64];
    __shared__ __attribute__((aligned(16))) short Bs[128 * 64];
    const int tid = threadIdx.x;
    const int lane = tid & 63;
    const int wave = tid >> 6;
    const int wm = wave >> 1, wn = wave & 1;
    const int l15 = lane & 15, g = lane >> 4;
    const int brow = blockIdx.y * 128;
    const int bcol = blockIdx.x * 128;

    f32x4 acc[4][4];
    #pragma unroll
    for (int m = 0; m < 4; ++m)
        #pragma unroll
        for (int n = 0; n < 4; ++n) acc[m][n] = (f32x4){0.f, 0.f, 0.f, 0.f};

    for (int k0 = 0; k0 < MD; k0 += 64) {
        short8 av[4], bv[4];
        #pragma unroll
        for (int i = 0; i < 4; ++i) {
            int u = tid + i * 256;
            int row = u >> 3, c16 = u & 7;
            av[i] = *(const short8*)(A  + (size_t)(brow + row) * MD + k0 + c16 * 8);
            bv[i] = *(const short8*)(Bt + (size_t)(bcol + row) * MD + k0 + c16 * 8);
        }
        __syncthreads();
        #pragma unroll
        for (int i = 0; i < 4; ++i) {
            *(short8*)&As[(tid + i * 256) * 8] = av[i];
            *(short8*)&Bs[(tid + i * 256) * 8] = bv[i];
        }
        __syncthreads();
        #pragma unroll
        for (int kk = 0; kk < 64; kk += 32) {
            short8 af[4], bf_[4];
            #pragma unroll
            for (int m = 0; m < 4; ++m)
                af[m] = *(const short8*)&As[(wm * 64 + m * 16 + l15) * 64 + kk + g * 8];
            #pragma unroll
            for (int n = 0; n < 4; ++n)
                bf_[n] = *(const short8*)&Bs[(wn * 64 + n * 16 + l15) * 64 + kk + g * 8];
            #pragma unroll
            for (int m = 0; m < 4; ++m)
                #pragma unroll
                for (int n = 0; n < 4; ++n)
                    acc[m][n] = __builtin_amdgcn_mfma_f32_16x16x32_bf16(af[m], bf_[n], acc[m][n], 0, 0, 0);
        }
    }

    #pragma unroll
    for (int m = 0; m < 4; ++m) {
        #pragma unroll
        for (int n = 0; n < 4; ++n) {
            const int col = bcol + wn * 64 + n * 16 + l15;
            const float bcol_v = bias[col];
            #pragma unroll
            for (int r = 0; r < 4; ++r) {
                const size_t row = (size_t)(brow + wm * 64 + m * 16 + 4 * g + r);
                float v = acc[m][n][r] + bcol_v;
                if (residual) v += residual[row * MD + col];
                if (Cb) Cb[row * MD + col] = f2b(v);
                else    Cf[row * MD + col] = v;
            }
        }
    }
}

// ---------------------------------------------------------------------------
// Flash attention, bf16 MFMA. Grid (16 qtiles, 64 bh), 256 thr = 4 waves.
// Per block: 128 q-rows (32/wave). KV tiles of 64. Swapped QK^T (K*Q^T) so
// P rows pack 4 consecutive kv per reg quad. All LDS XOR-swizzled per 16B
// unit: physical_unit = logical_unit ^ (row & 7).
// ---------------------------------------------------------------------------
__global__ __launch_bounds__(256, 2)
void attn_mfma(const unsigned short* __restrict__ qp,
               const unsigned short* __restrict__ kp,
               const unsigned short* __restrict__ vt,
               unsigned short* __restrict__ ao)
{
    __shared__ __attribute__((aligned(16))) short Qs[128 * 64];
    __shared__ __attribute__((aligned(16))) short Ks[64 * 64];
    __shared__ __attribute__((aligned(16))) short Vts[64 * 64];
    __shared__ __attribute__((aligned(16))) short Ps[128 * 64];

    const int tid = threadIdx.x;
    const int lane = tid & 63;
    const int wave = tid >> 6;
    const int l15 = lane & 15, g = lane >> 4;
    const int qt = blockIdx.x, bh = blockIdx.y;
    const int b = bh >> 4, h = bh & 15;
    const size_t rowbase = (size_t)b * SEQ;
    const int q0 = qt * 128;
    const int wq = wave * 32;

    // stage Q (scaled by 1/sqrt(64) = 0.125, exact in bf16)
    #pragma unroll
    for (int i = 0; i < 4; ++i) {
        int u = tid + i * 256;
        int row = u >> 3, c16 = u & 7;
        short8 v = *(const short8*)(qp + (rowbase + q0 + row) * MD + h * 64 + c16 * 8);
        short8 o;
        #pragma unroll
        for (int j = 0; j < 8; ++j)
            o[j] = (short)f2b(b2f((unsigned short)v[j]) * 0.125f);
        *(short8*)&Qs[(row * 8 + (c16 ^ (row & 7))) * 8] = o;
    }

    float mrun[2] = {-INFINITY, -INFINITY};
    float lrun[2] = {0.f, 0.f};
    f32x4 off[2][4];
    #pragma unroll
    for (int qf = 0; qf < 2; ++qf)
        #pragma unroll
        for (int df = 0; df < 4; ++df) off[qf][df] = (f32x4){0.f, 0.f, 0.f, 0.f};

    for (int kt = 0; kt < SEQ / 64; ++kt) {
        __syncthreads();   // prior tile's PV reads of Vts done
        #pragma unroll
        for (int i = 0; i < 2; ++i) {
            int u = tid + i * 256;
            int row = u >> 3, c16 = u & 7;
            short8 kv8 = *(const short8*)(kp + (rowbase + kt * 64 + row) * MD + h * 64 + c16 * 8);
            *(short8*)&Ks[(row * 8 + (c16 ^ (row & 7))) * 8] = kv8;
            short8 vv8 = *(const short8*)(vt + ((size_t)bh * 64 + row) * SEQ + kt * 64 + c16 * 8);
            *(short8*)&Vts[(row * 8 + (c16 ^ (row & 7))) * 8] = vv8;
        }
        __syncthreads();

        // S^T = K @ Q^T : sc[mf][nf], lane holds S^T[kv=mf*16+4g+r][q=wq+nf*16+l15]
        f32x4 sc[4][2];
        #pragma unroll
        for (int mf = 0; mf < 4; ++mf)
            #pragma unroll
            for (int nf = 0; nf < 2; ++nf) sc[mf][nf] = (f32x4){0.f, 0.f, 0.f, 0.f};
        #pragma unroll
        for (int kk = 0; kk < 64; kk += 32) {
            const int cu = (kk >> 3) + g;
            short8 af[4], bq[2];
            #pragma unroll
            for (int mf = 0; mf < 4; ++mf) {
                int row = mf * 16 + l15;
                af[mf] = *(const short8*)&Ks[(row * 8 + (cu ^ (row & 7))) * 8];
            }
            #pragma unroll
            for (int nf = 0; nf < 2; ++nf) {
                int row = wq + nf * 16 + l15;
                bq[nf] = *(const short8*)&Qs[(row * 8 + (cu ^ (row & 7))) * 8];
            }
            #pragma unroll
            for (int mf = 0; mf < 4; ++mf)
                #pragma unroll
                for (int nf = 0; nf < 2; ++nf)
                    sc[mf][nf] = __builtin_amdgcn_mfma_f32_16x16x32_bf16(af[mf], bq[nf], sc[mf][nf], 0, 0, 0);
        }

        // online softmax (lane owns q = wq + nf*16 + l15; kv spread over regs+g)
        float corr[2];
        #pragma unroll
        for (int nf = 0; nf < 2; ++nf) {
            float pm = -INFINITY;
            #pragma unroll
            for (int mf = 0; mf < 4; ++mf)
                #pragma unroll
                for (int r = 0; r < 4; ++r) pm = fmaxf(pm, sc[mf][nf][r]);
            pm = fmaxf(pm, __shfl_xor(pm, 16));
            pm = fmaxf(pm, __shfl_xor(pm, 32));
            float mnew = fmaxf(mrun[nf], pm);
            corr[nf] = __expf(mrun[nf] - mnew);
            mrun[nf] = mnew;
            float ps = 0.f;
            #pragma unroll
            for (int mf = 0; mf < 4; ++mf)
                #pragma unroll
                for (int r = 0; r < 4; ++r) {
                    float p = __expf(sc[mf][nf][r] - mnew);
                    sc[mf][nf][r] = p;
                    ps += p;
                }
            ps += __shfl_xor(ps, 16);
            ps += __shfl_xor(ps, 32);
            lrun[nf] = lrun[nf] * corr[nf] + ps;
        }

        // write P bf16 to LDS: P[q][kv], 4 consecutive kv per b64 write
        #pragma unroll
        for (int nf = 0; nf < 2; ++nf) {
            int row = wq + nf * 16 + l15;
            #pragma unroll
            for (int mf = 0; mf < 4; ++mf) {
                short4v pk;
                #pragma unroll
                for (int r = 0; r < 4; ++r) pk[r] = (short)f2b(sc[mf][nf][r]);
                int su = (mf * 2 + (g >> 1)) ^ (row & 7);
                *(short4v*)&Ps[row * 64 + su * 8 + (g & 1) * 4] = pk;
            }
        }

        // rescale O accumulator: corr for row 4g+r lives in lane (4g+r) of softmax view
        #pragma unroll
        for (int qf = 0; qf < 2; ++qf) {
            float cb = corr[qf];
            #pragma unroll
            for (int r = 0; r < 4; ++r) {
                float c = __shfl(cb, 4 * g + r);
                #pragma unroll
                for (int df = 0; df < 4; ++df) off[qf][df][r] *= c;
            }
        }

        // PV: O[q][d] += P[q][kv] @ V[kv][d]  (B from transposed-V LDS)
        #pragma unroll
        for (int kk = 0; kk < 64; kk += 32) {
            const int cu = (kk >> 3) + g;
            short8 pa[2], vb[4];
            #pragma unroll
            for (int qf = 0; qf < 2; ++qf) {
                int row = wq + qf * 16 + l15;
                pa[qf] = *(const short8*)&Ps[(row * 8 + (cu ^ (row & 7))) * 8];
            }
            #pragma unroll
            for (int df = 0; df < 4; ++df) {
                int d = df * 16 + l15;
                vb[df] = *(const short8*)&Vts[(d * 8 + (cu ^ (d & 7))) * 8];
            }
            #pragma unroll
            for (int qf = 0; qf < 2; ++qf)
                #pragma unroll
                for (int df = 0; df < 4; ++df)
                    off[qf][df] = __builtin_amdgcn_mfma_f32_16x16x32_bf16(pa[qf], vb[df], off[qf][df], 0, 0, 0);
        }
    }

    // normalize + store bf16
    #pragma unroll
    for (int qf = 0; qf < 2; ++qf) {
        float invq = 1.0f / lrun[qf];
        #pragma unroll
        for (int r = 0; r < 4; ++r) {
            float inv = __shfl(invq, 4 * g + r);
            const size_t row = rowbase + q0 + wq + qf * 16 + 4 * g + r;
            #pragma unroll
            for (int df = 0; df < 4; ++df) {
                float val = off[qf][df][r] * inv;
                ao[row * MD + h * 64 + df * 16 + l15] = f2b(val);
            }
        }
    }
}

// ---------------------------------------------------------------------------
// In-place LayerNorm over last dim (1024). One block per row, 256 threads.
// ---------------------------------------------------------------------------
__global__ __launch_bounds__(256)
void ln_kernel(float* __restrict__ X, const float* __restrict__ gamma,
               const float* __restrict__ beta)
{
    const int row = blockIdx.x;
    const int tid = threadIdx.x;
    float* px = X + (size_t)row * MD;
    f32x4 x = ((const f32x4*)px)[tid];
    float s  = x[0] + x[1] + x[2] + x[3];
    float ss = fmaf(x[0], x[0], fmaf(x[1], x[1], fmaf(x[2], x[2], x[3] * x[3])));
    #pragma unroll
    for (int off = 1; off < 64; off <<= 1) {
        s  += __shfl_xor(s,  off);
        ss += __shfl_xor(ss, off);
    }
    __shared__ float red[8];
    const int wid = tid >> 6;
    if ((tid & 63) == 0) { red[wid] = s; red[wid + 4] = ss; }
    __syncthreads();
    s  = red[0] + red[1] + red[2] + red[3];
    ss = red[4] + red[5] + red[6] + red[7];
    const float mu   = s * (1.0f / MD);
    const float var  = ss * (1.0f / MD) - mu * mu;
    const float rstd = rsqrtf(var + 1e-5f);
    f32x4 gm = ((const f32x4*)gamma)[tid];
    f32x4 be = ((const f32x4*)beta)[tid];
    f32x4 r;
    r[0] = (x[0] - mu) * rstd * gm[0] + be[0];
    r[1] = (x[1] - mu) * rstd * gm[1] + be[1];
    r[2] = (x[2] - mu) * rstd * gm[2] + be[2];
    r[3] = (x[3] - mu) * rstd * gm[3] + be[3];
    ((f32x4*)px)[tid] = r;
}

// ---------------------------------------------------------------------------
extern "C" void kernel_launch(void* const* d_in, const int* in_sizes, int n_in,
                              void* d_out, int out_size, void* d_ws, size_t ws_size,
                              hipStream_t stream)
{
    const float* query = (const float*)d_in[0];
    const float* key   = (const float*)d_in[1];
    const float* value = (const float*)d_in[2];
    const float* Wq = (const float*)d_in[3];
    const float* bq = (const float*)d_in[4];
    const float* Wk = (const float*)d_in[5];
    const float* bk = (const float*)d_in[6];
    const float* Wv = (const float*)d_in[7];
    const float* bv = (const float*)d_in[8];
    const float* Wo = (const float*)d_in[9];
    const float* bo = (const float*)d_in[10];
    const float* gamma = (const float*)d_in[11];
    const float* beta  = (const float*)d_in[12];
    float* out = (float*)d_out;

    const size_t NTOK = (size_t)BATCH * SEQ;            // 8192
    const size_t ACT  = NTOK * MD;                      // 8M elems

    unsigned short* qa  = (unsigned short*)d_ws;        // 16MB; later reused as vt
    unsigned short* ka  = qa + ACT;                     // 16MB; later reused as ao
    unsigned short* va  = ka + ACT;                     // 16MB
    unsigned short* WqT = va + ACT;                     // 2MB each
    unsigned short* WkT = WqT + (size_t)MD * MD;
    unsigned short* WvT = WkT + (size_t)MD * MD;
    unsigned short* WoT = WvT + (size_t)MD * MD;
    unsigned short* qp  = WoT + (size_t)MD * MD;        // 16MB
    unsigned short* kp  = qp + ACT;
    unsigned short* vp  = kp + ACT;
    unsigned short* vtb = qa;   // reuse (qa dead after Q-projection)
    unsigned short* ao  = ka;   // reuse (ka dead after K-projection)

    dim3 blk(256);

    convbf<<<4096, blk, 0, stream>>>(query, qa, (int)ACT);
    convbf<<<4096, blk, 0, stream>>>(key,   ka, (int)ACT);
    convbf<<<4096, blk, 0, stream>>>(value, va, (int)ACT);

    dim3 wg(16, 16);
    wtrans<<<wg, blk, 0, stream>>>(Wq, WqT);
    wtrans<<<wg, blk, 0, stream>>>(Wk, WkT);
    wtrans<<<wg, blk, 0, stream>>>(Wv, WvT);
    wtrans<<<wg, blk, 0, stream>>>(Wo, WoT);

    dim3 gg(MD / 128, NTOK / 128);   // (8, 64)
    gemm_bf16<<<gg, blk, 0, stream>>>(qa, WqT, bq, nullptr, qp, nullptr);
    gemm_bf16<<<gg, blk, 0, stream>>>(ka, WkT, bk, nullptr, kp, nullptr);
    gemm_bf16<<<gg, blk, 0, stream>>>(va, WvT, bv, nullptr, vp, nullptr);

    vtrans<<<dim3(SEQ / 64, 64), blk, 0, stream>>>(vp, vtb);

    attn_mfma<<<dim3(SEQ / 128, 64), blk, 0, stream>>>(qp, kp, vtb, ao);

    gemm_bf16<<<gg, blk, 0, stream>>>(ao, WoT, bo, query, nullptr, out);

    ln_kernel<<<NTOK, blk, 0, stream>>>(out, gamma, beta);
}

// Round 3
// 285.823 us; speedup vs baseline: 9.0651x; 1.2589x over previous
//
#include <hip/hip_runtime.h>
#include <math.h>

#define MD 1024
#define NH 16
#define HD 64
#define BATCH 4
#define SEQ 2048

typedef __attribute__((ext_vector_type(8))) short short8;
typedef __attribute__((ext_vector_type(4))) short short4v;
typedef __attribute__((ext_vector_type(4))) float f32x4;
typedef __attribute__((ext_vector_type(2))) unsigned int uint2v;

#define GLOAD16(gp, lp) __builtin_amdgcn_global_load_lds( \
    (const __attribute__((address_space(1))) void*)(gp),  \
    (__attribute__((address_space(3))) void*)(lp), 16, 0, 0)

__device__ inline unsigned short f2b(float f) {
    unsigned u = __builtin_bit_cast(unsigned, f);
    unsigned r = (u + 0x7fffu + ((u >> 16) & 1u)) >> 16;
    return (unsigned short)r;
}
__device__ inline float b2f(unsigned short s) {
    return __builtin_bit_cast(float, ((unsigned)s) << 16);
}

// ---------------------------------------------------------------------------
// fp32 -> bf16 convert for q,k,v activations in one launch (blockIdx.y picks)
// ---------------------------------------------------------------------------
__global__ __launch_bounds__(256)
void convbf3(const float* __restrict__ x0, const float* __restrict__ x1,
             const float* __restrict__ x2, unsigned short* __restrict__ y0,
             unsigned short* __restrict__ y1, unsigned short* __restrict__ y2,
             int n)
{
    const float* x = (blockIdx.y == 0) ? x0 : (blockIdx.y == 1) ? x1 : x2;
    unsigned short* y = (blockIdx.y == 0) ? y0 : (blockIdx.y == 1) ? y1 : y2;
    int i = (blockIdx.x * 256 + threadIdx.x) * 8;
    if (i >= n) return;
    f32x4 a = *(const f32x4*)(x + i);
    f32x4 b = *(const f32x4*)(x + i + 4);
    short8 o;
    o[0] = (short)f2b(a[0]); o[1] = (short)f2b(a[1]);
    o[2] = (short)f2b(a[2]); o[3] = (short)f2b(a[3]);
    o[4] = (short)f2b(b[0]); o[5] = (short)f2b(b[1]);
    o[6] = (short)f2b(b[2]); o[7] = (short)f2b(b[3]);
    *(short8*)(y + i) = o;
}

// ---------------------------------------------------------------------------
// W[K][N] fp32 -> WT[N][K] bf16, all four weights in one launch (blockIdx.z)
// ---------------------------------------------------------------------------
__global__ __launch_bounds__(256)
void wtrans4(const float* __restrict__ W0, const float* __restrict__ W1,
             const float* __restrict__ W2, const float* __restrict__ W3,
             unsigned short* __restrict__ T0, unsigned short* __restrict__ T1,
             unsigned short* __restrict__ T2, unsigned short* __restrict__ T3)
{
    const int z = blockIdx.z;
    const float* W = (z == 0) ? W0 : (z == 1) ? W1 : (z == 2) ? W2 : W3;
    unsigned short* WT = (z == 0) ? T0 : (z == 1) ? T1 : (z == 2) ? T2 : T3;
    __shared__ __attribute__((aligned(16))) float T[64][68];
    const int tid = threadIdx.x;
    const int nt = blockIdx.x, kt = blockIdx.y;
    #pragma unroll
    for (int i = 0; i < 4; ++i) {
        int u = tid + i * 256;
        int row = u >> 4, c4 = u & 15;
        f32x4 v = *(const f32x4*)(W + (size_t)(kt * 64 + row) * MD + nt * 64 + c4 * 4);
        *(f32x4*)&T[row][c4 * 4] = v;
    }
    __syncthreads();
    #pragma unroll
    for (int i = 0; i < 2; ++i) {
        int u = tid + i * 256;
        int n = u >> 3, c16 = u & 7;
        short8 o;
        #pragma unroll
        for (int j = 0; j < 8; ++j) o[j] = (short)f2b(T[c16 * 8 + j][n]);
        *(short8*)(WT + (size_t)(nt * 64 + n) * MD + kt * 64 + c16 * 8) = o;
    }
}

// ---------------------------------------------------------------------------
// vp[B*S][MD] bf16 -> vt[bh][d][s] bf16 (per-head transpose)
// ---------------------------------------------------------------------------
__global__ __launch_bounds__(256)
void vtrans(const unsigned short* __restrict__ vp, unsigned short* __restrict__ vt)
{
    __shared__ __attribute__((aligned(16))) short T[64][72];
    const int tid = threadIdx.x;
    const int st = blockIdx.x, bh = blockIdx.y;
    const int b = bh >> 4, h = bh & 15;
    #pragma unroll
    for (int i = 0; i < 2; ++i) {
        int u = tid + i * 256;
        int row = u >> 3, c16 = u & 7;
        short8 v = *(const short8*)(vp + ((size_t)b * SEQ + st * 64 + row) * MD + h * 64 + c16 * 8);
        *(short8*)&T[row][c16 * 8] = v;
    }
    __syncthreads();
    #pragma unroll
    for (int i = 0; i < 2; ++i) {
        int u = tid + i * 256;
        int d = u >> 3, c16 = u & 7;
        short8 o;
        #pragma unroll
        for (int j = 0; j < 8; ++j) o[j] = T[c16 * 8 + j][d];
        *(short8*)(vt + ((size_t)bh * 64 + d) * SEQ + st * 64 + c16 * 8) = o;
    }
}

// ---------------------------------------------------------------------------
// bf16 MFMA GEMM, m97 structure: 128x128 tile, BK=64, global_load_lds
// width-16 staging (linear LDS), 2 barriers/K-step, XCD-swizzled block id.
// ---------------------------------------------------------------------------
__global__ __launch_bounds__(256, 2)
void gemm_bf16(const unsigned short* __restrict__ A,
               const unsigned short* __restrict__ Bt,
               const float* __restrict__ bias,
               const float* __restrict__ residual,
               unsigned short* __restrict__ Cb,
               float* __restrict__ Cf)
{
    __shared__ __attribute__((aligned(16))) short As[128 * 64];
    __shared__ __attribute__((aligned(16))) short Bs[128 * 64];
    const int tid = threadIdx.x;
    const int lane = tid & 63;
    const int wave = tid >> 6;
    const int wm = wave >> 1, wn = wave & 1;
    const int l15 = lane & 15, g = lane >> 4;

    // XCD-aware swizzle (nwg = 8*64 = 512, divisible by 8 -> simple form OK)
    const int nbx = gridDim.x;
    const int bid = blockIdx.y * nbx + blockIdx.x;
    const int cpx = (nbx * gridDim.y) >> 3;
    const int swz = (bid & 7) * cpx + (bid >> 3);
    const int brow = (swz / nbx) * 128;
    const int bcol = (swz % nbx) * 128;

    f32x4 acc[4][4];
    #pragma unroll
    for (int m = 0; m < 4; ++m)
        #pragma unroll
        for (int n = 0; n < 4; ++n) acc[m][n] = (f32x4){0.f, 0.f, 0.f, 0.f};

    for (int k0 = 0; k0 < MD; k0 += 64) {
        __syncthreads();                       // prior iter's frag reads done
        #pragma unroll
        for (int i = 0; i < 4; ++i) {
            const int U = (i * 4 + wave) * 64 + lane;   // 0..1023 16B units
            const int row = U >> 3, c16 = U & 7;
            GLOAD16(A  + (size_t)(brow + row) * MD + k0 + c16 * 8, &As[U * 8]);
            GLOAD16(Bt + (size_t)(bcol + row) * MD + k0 + c16 * 8, &Bs[U * 8]);
        }
        __syncthreads();                       // vmcnt drained by compiler
        #pragma unroll
        for (int kk = 0; kk < 64; kk += 32) {
            short8 af[4], bf_[4];
            #pragma unroll
            for (int m = 0; m < 4; ++m)
                af[m] = *(const short8*)&As[(wm * 64 + m * 16 + l15) * 64 + kk + g * 8];
            #pragma unroll
            for (int n = 0; n < 4; ++n)
                bf_[n] = *(const short8*)&Bs[(wn * 64 + n * 16 + l15) * 64 + kk + g * 8];
            #pragma unroll
            for (int m = 0; m < 4; ++m)
                #pragma unroll
                for (int n = 0; n < 4; ++n)
                    acc[m][n] = __builtin_amdgcn_mfma_f32_16x16x32_bf16(af[m], bf_[n], acc[m][n], 0, 0, 0);
        }
    }

    #pragma unroll
    for (int m = 0; m < 4; ++m) {
        #pragma unroll
        for (int n = 0; n < 4; ++n) {
            const int col = bcol + wn * 64 + n * 16 + l15;
            const float bcol_v = bias[col];
            #pragma unroll
            for (int r = 0; r < 4; ++r) {
                const size_t row = (size_t)(brow + wm * 64 + m * 16 + 4 * g + r);
                float v = acc[m][n][r] + bcol_v;
                if (residual) v += residual[row * MD + col];
                if (Cb) Cb[row * MD + col] = f2b(v);
                else    Cf[row * MD + col] = v;
            }
        }
    }
}

// ---------------------------------------------------------------------------
// Flash attention, bf16 MFMA, exp2-domain softmax, defer-max, reg-prefetched
// K/V (T14), Q fragments hoisted to regs, Qs/Ps aliased (LDS 32 KB).
// Grid (16 qtiles, 64 bh), 256 thr = 4 waves, 32 q-rows/wave, KV tile 64.
// ---------------------------------------------------------------------------
__global__ __launch_bounds__(256, 2)
void attn_mfma(const unsigned short* __restrict__ qp,
               const unsigned short* __restrict__ kp,
               const unsigned short* __restrict__ vt,
               unsigned short* __restrict__ ao)
{
    __shared__ __attribute__((aligned(16))) short QPs[128 * 64];  // Q, then P
    __shared__ __attribute__((aligned(16))) short Ks[64 * 64];
    __shared__ __attribute__((aligned(16))) short Vts[64 * 64];

    const int tid = threadIdx.x;
    const int lane = tid & 63;
    const int wave = tid >> 6;
    const int l15 = lane & 15, g = lane >> 4;
    const int qt = blockIdx.x, bh = blockIdx.y;
    const int b = bh >> 4, h = bh & 15;
    const size_t rowbase = (size_t)b * SEQ;
    const int q0 = qt * 128;
    const int wq = wave * 32;

    // stage Q scaled by (1/8)*log2(e): scores land in log2 domain
    const float qscale = 0.125f * 1.44269504088896f;
    #pragma unroll
    for (int i = 0; i < 4; ++i) {
        int u = tid + i * 256;
        int row = u >> 3, c16 = u & 7;
        short8 v = *(const short8*)(qp + (rowbase + q0 + row) * MD + h * 64 + c16 * 8);
        short8 o;
        #pragma unroll
        for (int j = 0; j < 8; ++j)
            o[j] = (short)f2b(b2f((unsigned short)v[j]) * qscale);
        *(short8*)&QPs[(row * 8 + (c16 ^ (row & 7))) * 8] = o;
    }
    __syncthreads();

    // hoist this wave's Q fragments to registers (wave-own rows)
    short8 qreg[2][2];
    #pragma unroll
    for (int nf = 0; nf < 2; ++nf)
        #pragma unroll
        for (int ki = 0; ki < 2; ++ki) {
            int row = wq + nf * 16 + l15;
            int cu = ki * 4 + g;
            qreg[nf][ki] = *(const short8*)&QPs[(row * 8 + (cu ^ (row & 7))) * 8];
        }

    float mrun[2] = {-INFINITY, -INFINITY};
    float lrun[2] = {0.f, 0.f};
    f32x4 off[2][4];
    #pragma unroll
    for (int qf = 0; qf < 2; ++qf)
        #pragma unroll
        for (int df = 0; df < 4; ++df) off[qf][df] = (f32x4){0.f, 0.f, 0.f, 0.f};

    // prologue: prefetch KV tile 0 into registers
    short8 kreg[2], vreg[2];
    #pragma unroll
    for (int i = 0; i < 2; ++i) {
        int u = tid + i * 256;
        int row = u >> 3, c16 = u & 7;
        kreg[i] = *(const short8*)(kp + (rowbase + row) * MD + h * 64 + c16 * 8);
        vreg[i] = *(const short8*)(vt + ((size_t)bh * 64 + row) * SEQ + c16 * 8);
    }

    for (int kt = 0; kt < SEQ / 64; ++kt) {
        // write staged regs -> LDS (XOR-swizzled)
        #pragma unroll
        for (int i = 0; i < 2; ++i) {
            int u = tid + i * 256;
            int row = u >> 3, c16 = u & 7;
            *(short8*)&Ks [(row * 8 + (c16 ^ (row & 7))) * 8] = kreg[i];
            *(short8*)&Vts[(row * 8 + (c16 ^ (row & 7))) * 8] = vreg[i];
        }
        __syncthreads();

        // T14: issue next tile's loads now; latency hides under compute
        if (kt + 1 < SEQ / 64) {
            #pragma unroll
            for (int i = 0; i < 2; ++i) {
                int u = tid + i * 256;
                int row = u >> 3, c16 = u & 7;
                kreg[i] = *(const short8*)(kp + (rowbase + (kt + 1) * 64 + row) * MD + h * 64 + c16 * 8);
                vreg[i] = *(const short8*)(vt + ((size_t)bh * 64 + row) * SEQ + (kt + 1) * 64 + c16 * 8);
            }
        }

        // S^T = K @ Q^T : lane holds S^T[kv = mf*16+4g+r][q = wq+nf*16+l15]
        f32x4 sc[4][2];
        #pragma unroll
        for (int mf = 0; mf < 4; ++mf)
            #pragma unroll
            for (int nf = 0; nf < 2; ++nf) sc[mf][nf] = (f32x4){0.f, 0.f, 0.f, 0.f};
        __builtin_amdgcn_s_setprio(1);
        #pragma unroll
        for (int ki = 0; ki < 2; ++ki) {
            const int cu = ki * 4 + g;
            short8 af[4];
            #pragma unroll
            for (int mf = 0; mf < 4; ++mf) {
                int row = mf * 16 + l15;
                af[mf] = *(const short8*)&Ks[(row * 8 + (cu ^ (row & 7))) * 8];
            }
            #pragma unroll
            for (int mf = 0; mf < 4; ++mf)
                #pragma unroll
                for (int nf = 0; nf < 2; ++nf)
                    sc[mf][nf] = __builtin_amdgcn_mfma_f32_16x16x32_bf16(af[mf], qreg[nf][ki], sc[mf][nf], 0, 0, 0);
        }
        __builtin_amdgcn_s_setprio(0);

        // online softmax in log2 domain, defer-max (THR = 8 -> P <= 256)
        float pmax[2];
        #pragma unroll
        for (int nf = 0; nf < 2; ++nf) {
            float pm = -INFINITY;
            #pragma unroll
            for (int mf = 0; mf < 4; ++mf)
                #pragma unroll
                for (int r = 0; r < 4; ++r) pm = fmaxf(pm, sc[mf][nf][r]);
            pm = fmaxf(pm, __shfl_xor(pm, 16));
            pm = fmaxf(pm, __shfl_xor(pm, 32));
            pmax[nf] = pm;
        }
        const int defer = (pmax[0] <= mrun[0] + 8.0f) && (pmax[1] <= mrun[1] + 8.0f);
        if (!__all(defer)) {
            float corr[2];
            #pragma unroll
            for (int nf = 0; nf < 2; ++nf) {
                float mnew = fmaxf(mrun[nf], pmax[nf]);
                corr[nf] = __builtin_amdgcn_exp2f(mrun[nf] - mnew);
                mrun[nf] = mnew;
                lrun[nf] *= corr[nf];
            }
            #pragma unroll
            for (int qf = 0; qf < 2; ++qf)
                #pragma unroll
                for (int r = 0; r < 4; ++r) {
                    float c = __shfl(corr[qf], 4 * g + r);
                    #pragma unroll
                    for (int df = 0; df < 4; ++df) off[qf][df][r] *= c;
                }
        }
        #pragma unroll
        for (int nf = 0; nf < 2; ++nf) {
            float ps = 0.f;
            #pragma unroll
            for (int mf = 0; mf < 4; ++mf)
                #pragma unroll
                for (int r = 0; r < 4; ++r) {
                    float p = __builtin_amdgcn_exp2f(sc[mf][nf][r] - mrun[nf]);
                    sc[mf][nf][r] = p;
                    ps += p;
                }
            ps += __shfl_xor(ps, 16);
            ps += __shfl_xor(ps, 32);
            lrun[nf] += ps;
        }

        // pack P -> bf16 via v_cvt_pk_bf16_f32, write to QPs (wave-own rows)
        #pragma unroll
        for (int nf = 0; nf < 2; ++nf) {
            int row = wq + nf * 16 + l15;
            #pragma unroll
            for (int mf = 0; mf < 4; ++mf) {
                unsigned p01, p23;
                asm("v_cvt_pk_bf16_f32 %0, %1, %2" : "=v"(p01) : "v"(sc[mf][nf][0]), "v"(sc[mf][nf][1]));
                asm("v_cvt_pk_bf16_f32 %0, %1, %2" : "=v"(p23) : "v"(sc[mf][nf][2]), "v"(sc[mf][nf][3]));
                uint2v pk = {p01, p23};
                int su = (mf * 2 + (g >> 1)) ^ (row & 7);
                *(uint2v*)&QPs[row * 64 + su * 8 + (g & 1) * 4] = pk;
            }
        }

        // PV: O[q][d] += P[q][kv] @ Vt[kv][d]
        __builtin_amdgcn_s_setprio(1);
        #pragma unroll
        for (int ki = 0; ki < 2; ++ki) {
            const int cu = ki * 4 + g;
            short8 pa[2], vb[4];
            #pragma unroll
            for (int qf = 0; qf < 2; ++qf) {
                int row = wq + qf * 16 + l15;
                pa[qf] = *(const short8*)&QPs[(row * 8 + (cu ^ (row & 7))) * 8];
            }
            #pragma unroll
            for (int df = 0; df < 4; ++df) {
                int d = df * 16 + l15;
                vb[df] = *(const short8*)&Vts[(d * 8 + (cu ^ (d & 7))) * 8];
            }
            #pragma unroll
            for (int qf = 0; qf < 2; ++qf)
                #pragma unroll
                for (int df = 0; df < 4; ++df)
                    off[qf][df] = __builtin_amdgcn_mfma_f32_16x16x32_bf16(pa[qf], vb[df], off[qf][df], 0, 0, 0);
        }
        __builtin_amdgcn_s_setprio(0);
        __syncthreads();   // Ks/Vts reads done before next iter's writes
    }

    // normalize + store bf16
    #pragma unroll
    for (int qf = 0; qf < 2; ++qf) {
        float invq = 1.0f / lrun[qf];
        #pragma unroll
        for (int r = 0; r < 4; ++r) {
            float inv = __shfl(invq, 4 * g + r);
            const size_t row = rowbase + q0 + wq + qf * 16 + 4 * g + r;
            #pragma unroll
            for (int df = 0; df < 4; ++df) {
                float val = off[qf][df][r] * inv;
                ao[row * MD + h * 64 + df * 16 + l15] = f2b(val);
            }
        }
    }
}

// ---------------------------------------------------------------------------
// In-place LayerNorm over last dim (1024). One block per row, 256 threads.
// ---------------------------------------------------------------------------
__global__ __launch_bounds__(256)
void ln_kernel(float* __restrict__ X, const float* __restrict__ gamma,
               const float* __restrict__ beta)
{
    const int row = blockIdx.x;
    const int tid = threadIdx.x;
    float* px = X + (size_t)row * MD;
    f32x4 x = ((const f32x4*)px)[tid];
    float s  = x[0] + x[1] + x[2] + x[3];
    float ss = fmaf(x[0], x[0], fmaf(x[1], x[1], fmaf(x[2], x[2], x[3] * x[3])));
    #pragma unroll
    for (int off = 1; off < 64; off <<= 1) {
        s  += __shfl_xor(s,  off);
        ss += __shfl_xor(ss, off);
    }
    __shared__ float red[8];
    const int wid = tid >> 6;
    if ((tid & 63) == 0) { red[wid] = s; red[wid + 4] = ss; }
    __syncthreads();
    s  = red[0] + red[1] + red[2] + red[3];
    ss = red[4] + red[5] + red[6] + red[7];
    const float mu   = s * (1.0f / MD);
    const float var  = ss * (1.0f / MD) - mu * mu;
    const float rstd = rsqrtf(var + 1e-5f);
    f32x4 gm = ((const f32x4*)gamma)[tid];
    f32x4 be = ((const f32x4*)beta)[tid];
    f32x4 r;
    r[0] = (x[0] - mu) * rstd * gm[0] + be[0];
    r[1] = (x[1] - mu) * rstd * gm[1] + be[1];
    r[2] = (x[2] - mu) * rstd * gm[2] + be[2];
    r[3] = (x[3] - mu) * rstd * gm[3] + be[3];
    ((f32x4*)px)[tid] = r;
}

// ---------------------------------------------------------------------------
extern "C" void kernel_launch(void* const* d_in, const int* in_sizes, int n_in,
                              void* d_out, int out_size, void* d_ws, size_t ws_size,
                              hipStream_t stream)
{
    const float* query = (const float*)d_in[0];
    const float* key   = (const float*)d_in[1];
    const float* value = (const float*)d_in[2];
    const float* Wq = (const float*)d_in[3];
    const float* bq = (const float*)d_in[4];
    const float* Wk = (const float*)d_in[5];
    const float* bk = (const float*)d_in[6];
    const float* Wv = (const float*)d_in[7];
    const float* bv = (const float*)d_in[8];
    const float* Wo = (const float*)d_in[9];
    const float* bo = (const float*)d_in[10];
    const float* gamma = (const float*)d_in[11];
    const float* beta  = (const float*)d_in[12];
    float* out = (float*)d_out;

    const size_t NTOK = (size_t)BATCH * SEQ;            // 8192
    const size_t ACT  = NTOK * MD;                      // 8M elems

    unsigned short* qa  = (unsigned short*)d_ws;        // 16MB; later reused as vt
    unsigned short* ka  = qa + ACT;                     // 16MB; later reused as ao
    unsigned short* va  = ka + ACT;                     // 16MB
    unsigned short* WqT = va + ACT;                     // 2MB each
    unsigned short* WkT = WqT + (size_t)MD * MD;
    unsigned short* WvT = WkT + (size_t)MD * MD;
    unsigned short* WoT = WvT + (size_t)MD * MD;
    unsigned short* qp  = WoT + (size_t)MD * MD;        // 16MB
    unsigned short* kp  = qp + ACT;
    unsigned short* vp  = kp + ACT;
    unsigned short* vtb = qa;   // reuse (qa dead after Q-projection)
    unsigned short* ao  = ka;   // reuse (ka dead after K-projection)

    dim3 blk(256);

    convbf3<<<dim3(4096, 3), blk, 0, stream>>>(query, key, value, qa, ka, va, (int)ACT);
    wtrans4<<<dim3(16, 16, 4), blk, 0, stream>>>(Wq, Wk, Wv, Wo, WqT, WkT, WvT, WoT);

    dim3 gg(MD / 128, NTOK / 128);   // (8, 64) -> 512 blocks
    gemm_bf16<<<gg, blk, 0, stream>>>(qa, WqT, bq, nullptr, qp, nullptr);
    gemm_bf16<<<gg, blk, 0, stream>>>(ka, WkT, bk, nullptr, kp, nullptr);
    gemm_bf16<<<gg, blk, 0, stream>>>(va, WvT, bv, nullptr, vp, nullptr);

    vtrans<<<dim3(SEQ / 64, 64), blk, 0, stream>>>(vp, vtb);

    attn_mfma<<<dim3(SEQ / 128, 64), blk, 0, stream>>>(qp, kp, vtb, ao);

    gemm_bf16<<<gg, blk, 0, stream>>>(ao, WoT, bo, query, nullptr, out);

    ln_kernel<<<NTOK, blk, 0, stream>>>(out, gamma, beta);
}

// Round 4
// 248.899 us; speedup vs baseline: 10.4100x; 1.1483x over previous
//
#include <hip/hip_runtime.h>
#include <math.h>

#define MD 1024
#define NH 16
#define HD 64
#define BATCH 4
#define SEQ 2048

typedef __attribute__((ext_vector_type(8))) short short8;
typedef __attribute__((ext_vector_type(4))) short short4v;
typedef __attribute__((ext_vector_type(4))) float f32x4;
typedef __attribute__((ext_vector_type(2))) unsigned int uint2v;

#define GLOAD16(gp, lp) __builtin_amdgcn_global_load_lds( \
    (const __attribute__((address_space(1))) void*)(gp),  \
    (__attribute__((address_space(3))) void*)(lp), 16, 0, 0)

__device__ inline unsigned short f2b(float f) {
    unsigned u = __builtin_bit_cast(unsigned, f);
    unsigned r = (u + 0x7fffu + ((u >> 16) & 1u)) >> 16;
    return (unsigned short)r;
}
__device__ inline float b2f(unsigned short s) {
    return __builtin_bit_cast(float, ((unsigned)s) << 16);
}

// ---------------------------------------------------------------------------
// Fused prep: y<3 -> fp32->bf16 convert of q/k/v activations;
//             y==3 -> W[K][N] fp32 -> WT[N][K] bf16 for all 4 weights.
// Grid (4096, 4).
// ---------------------------------------------------------------------------
__global__ __launch_bounds__(256)
void prep_kernel(const float* __restrict__ x0, const float* __restrict__ x1,
                 const float* __restrict__ x2, unsigned short* __restrict__ y0,
                 unsigned short* __restrict__ y1, unsigned short* __restrict__ y2,
                 int n,
                 const float* __restrict__ W0, const float* __restrict__ W1,
                 const float* __restrict__ W2, const float* __restrict__ W3,
                 unsigned short* __restrict__ T0, unsigned short* __restrict__ T1,
                 unsigned short* __restrict__ T2, unsigned short* __restrict__ T3)
{
    __shared__ __attribute__((aligned(16))) float T[64][68];
    const int tid = threadIdx.x;
    if (blockIdx.y < 3) {
        const float* x = (blockIdx.y == 0) ? x0 : (blockIdx.y == 1) ? x1 : x2;
        unsigned short* y = (blockIdx.y == 0) ? y0 : (blockIdx.y == 1) ? y1 : y2;
        int i = (blockIdx.x * 256 + tid) * 8;
        if (i >= n) return;
        f32x4 a = *(const f32x4*)(x + i);
        f32x4 b = *(const f32x4*)(x + i + 4);
        short8 o;
        o[0] = (short)f2b(a[0]); o[1] = (short)f2b(a[1]);
        o[2] = (short)f2b(a[2]); o[3] = (short)f2b(a[3]);
        o[4] = (short)f2b(b[0]); o[5] = (short)f2b(b[1]);
        o[6] = (short)f2b(b[2]); o[7] = (short)f2b(b[3]);
        *(short8*)(y + i) = o;
        return;
    }
    // wtrans path: 4 weights x 256 tiles
    const int bx = blockIdx.x;
    if (bx >= 1024) return;
    const int z = bx >> 8, t = bx & 255;
    const int nt = t & 15, kt = t >> 4;
    const float* W = (z == 0) ? W0 : (z == 1) ? W1 : (z == 2) ? W2 : W3;
    unsigned short* WT = (z == 0) ? T0 : (z == 1) ? T1 : (z == 2) ? T2 : T3;
    #pragma unroll
    for (int i = 0; i < 4; ++i) {
        int u = tid + i * 256;
        int row = u >> 4, c4 = u & 15;
        f32x4 v = *(const f32x4*)(W + (size_t)(kt * 64 + row) * MD + nt * 64 + c4 * 4);
        *(f32x4*)&T[row][c4 * 4] = v;
    }
    __syncthreads();
    #pragma unroll
    for (int i = 0; i < 2; ++i) {
        int u = tid + i * 256;
        int nn = u >> 3, c16 = u & 7;
        short8 o;
        #pragma unroll
        for (int j = 0; j < 8; ++j) o[j] = (short)f2b(T[c16 * 8 + j][nn]);
        *(short8*)(WT + (size_t)(nt * 64 + nn) * MD + kt * 64 + c16 * 8) = o;
    }
}

// ---------------------------------------------------------------------------
// vp[B*S][MD] bf16 -> vt[bh][d][s] bf16 (per-head transpose)
// ---------------------------------------------------------------------------
__global__ __launch_bounds__(256)
void vtrans(const unsigned short* __restrict__ vp, unsigned short* __restrict__ vt)
{
    __shared__ __attribute__((aligned(16))) short T[64][72];
    const int tid = threadIdx.x;
    const int st = blockIdx.x, bh = blockIdx.y;
    const int b = bh >> 4, h = bh & 15;
    #pragma unroll
    for (int i = 0; i < 2; ++i) {
        int u = tid + i * 256;
        int row = u >> 3, c16 = u & 7;
        short8 v = *(const short8*)(vp + ((size_t)b * SEQ + st * 64 + row) * MD + h * 64 + c16 * 8);
        *(short8*)&T[row][c16 * 8] = v;
    }
    __syncthreads();
    #pragma unroll
    for (int i = 0; i < 2; ++i) {
        int u = tid + i * 256;
        int d = u >> 3, c16 = u & 7;
        short8 o;
        #pragma unroll
        for (int j = 0; j < 8; ++j) o[j] = T[c16 * 8 + j][d];
        *(short8*)(vt + ((size_t)bh * 64 + d) * SEQ + st * 64 + c16 * 8) = o;
    }
}

// ---------------------------------------------------------------------------
// bf16 MFMA GEMM body, m97 structure: 128x128 tile, BK=64, global_load_lds
// width-16 staging (linear LDS), 2 barriers/K-step, XCD-swizzled block id.
// ---------------------------------------------------------------------------
__device__ __forceinline__
void gemm_body(const unsigned short* __restrict__ A,
               const unsigned short* __restrict__ Bt,
               const float* __restrict__ bias,
               const float* __restrict__ residual,
               unsigned short* __restrict__ Cb,
               float* __restrict__ Cf,
               short* As, short* Bs)
{
    const int tid = threadIdx.x;
    const int lane = tid & 63;
    const int wave = tid >> 6;
    const int wm = wave >> 1, wn = wave & 1;
    const int l15 = lane & 15, g = lane >> 4;

    // XCD-aware swizzle (nwg per z-slice = 8*64 = 512, divisible by 8)
    const int nbx = gridDim.x;
    const int bid = blockIdx.y * nbx + blockIdx.x;
    const int cpx = (nbx * gridDim.y) >> 3;
    const int swz = (bid & 7) * cpx + (bid >> 3);
    const int brow = (swz / nbx) * 128;
    const int bcol = (swz % nbx) * 128;

    f32x4 acc[4][4];
    #pragma unroll
    for (int m = 0; m < 4; ++m)
        #pragma unroll
        for (int n = 0; n < 4; ++n) acc[m][n] = (f32x4){0.f, 0.f, 0.f, 0.f};

    for (int k0 = 0; k0 < MD; k0 += 64) {
        __syncthreads();
        #pragma unroll
        for (int i = 0; i < 4; ++i) {
            const int U = (i * 4 + wave) * 64 + lane;
            const int row = U >> 3, c16 = U & 7;
            GLOAD16(A  + (size_t)(brow + row) * MD + k0 + c16 * 8, &As[U * 8]);
            GLOAD16(Bt + (size_t)(bcol + row) * MD + k0 + c16 * 8, &Bs[U * 8]);
        }
        __syncthreads();
        #pragma unroll
        for (int kk = 0; kk < 64; kk += 32) {
            short8 af[4], bf_[4];
            #pragma unroll
            for (int m = 0; m < 4; ++m)
                af[m] = *(const short8*)&As[(wm * 64 + m * 16 + l15) * 64 + kk + g * 8];
            #pragma unroll
            for (int n = 0; n < 4; ++n)
                bf_[n] = *(const short8*)&Bs[(wn * 64 + n * 16 + l15) * 64 + kk + g * 8];
            #pragma unroll
            for (int m = 0; m < 4; ++m)
                #pragma unroll
                for (int n = 0; n < 4; ++n)
                    acc[m][n] = __builtin_amdgcn_mfma_f32_16x16x32_bf16(af[m], bf_[n], acc[m][n], 0, 0, 0);
        }
    }

    #pragma unroll
    for (int m = 0; m < 4; ++m) {
        #pragma unroll
        for (int n = 0; n < 4; ++n) {
            const int col = bcol + wn * 64 + n * 16 + l15;
            const float bcol_v = bias[col];
            #pragma unroll
            for (int r = 0; r < 4; ++r) {
                const size_t row = (size_t)(brow + wm * 64 + m * 16 + 4 * g + r);
                float v = acc[m][n][r] + bcol_v;
                if (residual) v += residual[row * MD + col];
                if (Cb) Cb[row * MD + col] = f2b(v);
                else    Cf[row * MD + col] = v;
            }
        }
    }
}

// Q/K/V projections in one launch; blockIdx.z selects the triple.
__global__ __launch_bounds__(256, 2)
void gemm_qkv(const unsigned short* __restrict__ A0, const unsigned short* __restrict__ A1,
              const unsigned short* __restrict__ A2,
              const unsigned short* __restrict__ B0, const unsigned short* __restrict__ B1,
              const unsigned short* __restrict__ B2,
              const float* __restrict__ b0, const float* __restrict__ b1,
              const float* __restrict__ b2,
              unsigned short* __restrict__ C0, unsigned short* __restrict__ C1,
              unsigned short* __restrict__ C2)
{
    __shared__ __attribute__((aligned(16))) short As[128 * 64];
    __shared__ __attribute__((aligned(16))) short Bs[128 * 64];
    const int z = blockIdx.z;
    const unsigned short* A  = (z == 0) ? A0 : (z == 1) ? A1 : A2;
    const unsigned short* Bt = (z == 0) ? B0 : (z == 1) ? B1 : B2;
    const float* bias        = (z == 0) ? b0 : (z == 1) ? b1 : b2;
    unsigned short* C        = (z == 0) ? C0 : (z == 1) ? C1 : C2;
    gemm_body(A, Bt, bias, nullptr, C, nullptr, As, Bs);
}

// O-projection: fp32 out + residual.
__global__ __launch_bounds__(256, 2)
void gemm_o(const unsigned short* __restrict__ A, const unsigned short* __restrict__ Bt,
            const float* __restrict__ bias, const float* __restrict__ residual,
            float* __restrict__ Cf)
{
    __shared__ __attribute__((aligned(16))) short As[128 * 64];
    __shared__ __attribute__((aligned(16))) short Bs[128 * 64];
    gemm_body(A, Bt, bias, residual, nullptr, Cf, As, Bs);
}

// ---------------------------------------------------------------------------
// Flash attention, bf16 MFMA. Double-buffered K/V LDS, ONE barrier per tile
// (write buf[nxt] before barrier, read buf after). exp2-domain softmax,
// defer-max, Q in regs, P wave-private in LDS, row-sums via mfma(P, ones)
// landing directly in O-layout (no sum shfls, no final inv shfl).
// Grid (16 qtiles, 64 bh), 256 thr = 4 waves, 32 q-rows/wave, KV tile 64.
// ---------------------------------------------------------------------------
__global__ __launch_bounds__(256, 2)
void attn_mfma(const unsigned short* __restrict__ qp,
               const unsigned short* __restrict__ kp,
               const unsigned short* __restrict__ vt,
               unsigned short* __restrict__ ao)
{
    __shared__ __attribute__((aligned(16))) short QPs[128 * 64];   // Q then P
    __shared__ __attribute__((aligned(16))) short Ks[2][64 * 64];
    __shared__ __attribute__((aligned(16))) short Vts[2][64 * 64];

    const int tid = threadIdx.x;
    const int lane = tid & 63;
    const int wave = tid >> 6;
    const int l15 = lane & 15, g = lane >> 4;
    const int qt = blockIdx.x, bh = blockIdx.y;
    const int b = bh >> 4, h = bh & 15;
    const size_t rowbase = (size_t)b * SEQ;
    const int q0 = qt * 128;
    const int wq = wave * 32;
    const int NT = SEQ / 64;

    // staging geometry (loop-invariant)
    const int r0 = tid >> 3, c16 = tid & 7;            // i=0: row r0
    const int r1 = (tid + 256) >> 3;                   // i=1: row r1 (c16 same)
    const int lds0 = (r0 * 8 + (c16 ^ (r0 & 7))) * 8;
    const int lds1 = (r1 * 8 + (c16 ^ (r1 & 7))) * 8;
    const unsigned short* kbase = kp + (rowbase + r0) * MD + h * 64 + c16 * 8;
    const unsigned short* vbase = vt + ((size_t)bh * 64 + r0) * SEQ + c16 * 8;

    // ---- stage Q scaled by (1/8)*log2(e): scores land in log2 domain ----
    const float qscale = 0.125f * 1.44269504088896f;
    #pragma unroll
    for (int i = 0; i < 4; ++i) {
        int u = tid + i * 256;
        int row = u >> 3, cc = u & 7;
        short8 v = *(const short8*)(qp + (rowbase + q0 + row) * MD + h * 64 + cc * 8);
        short8 o;
        #pragma unroll
        for (int j = 0; j < 8; ++j)
            o[j] = (short)f2b(b2f((unsigned short)v[j]) * qscale);
        *(short8*)&QPs[(row * 8 + (cc ^ (row & 7))) * 8] = o;
    }

    // ---- stage KV tile 0 into buf 0 ----
    {
        short8 k0v = *(const short8*)(kbase);
        short8 k1v = *(const short8*)(kbase + 32 * MD);
        short8 v0v = *(const short8*)(vbase);
        short8 v1v = *(const short8*)(vbase + 32 * SEQ);
        *(short8*)&Ks[0][lds0]  = k0v;
        *(short8*)&Ks[0][lds1]  = k1v;
        *(short8*)&Vts[0][lds0] = v0v;
        *(short8*)&Vts[0][lds1] = v1v;
    }
    __syncthreads();

    // hoist this wave's Q fragments (wave-own rows of QPs)
    short8 qreg[2][2];
    #pragma unroll
    for (int nf = 0; nf < 2; ++nf)
        #pragma unroll
        for (int ki = 0; ki < 2; ++ki) {
            int row = wq + nf * 16 + l15;
            int cu = ki * 4 + g;
            qreg[nf][ki] = *(const short8*)&QPs[(row * 8 + (cu ^ (row & 7))) * 8];
        }

    // ones B-fragment for row-sum MFMA (bf16 1.0 = 0x3F80)
    short8 ones;
    #pragma unroll
    for (int j = 0; j < 8; ++j) ones[j] = (short)0x3F80;

    float mrun[2] = {-INFINITY, -INFINITY};
    f32x4 lrun[2];                         // O-layout row-sums (rows 4g+r)
    f32x4 off[2][4];
    #pragma unroll
    for (int qf = 0; qf < 2; ++qf) {
        lrun[qf] = (f32x4){0.f, 0.f, 0.f, 0.f};
        #pragma unroll
        for (int df = 0; df < 4; ++df) off[qf][df] = (f32x4){0.f, 0.f, 0.f, 0.f};
    }

    for (int kt = 0; kt < NT; ++kt) {
        const int cur = kt & 1;

        // prefetch next tile into regs (latency hides under QK+softmax+PV)
        short8 kreg0, kreg1, vreg0, vreg1;
        if (kt + 1 < NT) {
            const unsigned short* kb = kbase + (size_t)(kt + 1) * 64 * MD;
            const unsigned short* vb = vbase + (kt + 1) * 64;
            kreg0 = *(const short8*)(kb);
            kreg1 = *(const short8*)(kb + 32 * MD);
            vreg0 = *(const short8*)(vb);
            vreg1 = *(const short8*)(vb + 32 * SEQ);
        }

        // ---- S^T = K @ Q^T ----
        f32x4 sc[4][2];
        #pragma unroll
        for (int mf = 0; mf < 4; ++mf)
            #pragma unroll
            for (int nf = 0; nf < 2; ++nf) sc[mf][nf] = (f32x4){0.f, 0.f, 0.f, 0.f};
        __builtin_amdgcn_s_setprio(1);
        #pragma unroll
        for (int ki = 0; ki < 2; ++ki) {
            const int cu = ki * 4 + g;
            short8 af[4];
            #pragma unroll
            for (int mf = 0; mf < 4; ++mf) {
                int row = mf * 16 + l15;
                af[mf] = *(const short8*)&Ks[cur][(row * 8 + (cu ^ (row & 7))) * 8];
            }
            #pragma unroll
            for (int mf = 0; mf < 4; ++mf)
                #pragma unroll
                for (int nf = 0; nf < 2; ++nf)
                    sc[mf][nf] = __builtin_amdgcn_mfma_f32_16x16x32_bf16(af[mf], qreg[nf][ki], sc[mf][nf], 0, 0, 0);
        }
        __builtin_amdgcn_s_setprio(0);

        // ---- online softmax (log2 domain), defer-max THR=8 ----
        float pmax[2];
        #pragma unroll
        for (int nf = 0; nf < 2; ++nf) {
            float pm = -INFINITY;
            #pragma unroll
            for (int mf = 0; mf < 4; ++mf)
                #pragma unroll
                for (int r = 0; r < 4; ++r) pm = fmaxf(pm, sc[mf][nf][r]);
            pm = fmaxf(pm, __shfl_xor(pm, 16));
            pm = fmaxf(pm, __shfl_xor(pm, 32));
            pmax[nf] = pm;
        }
        const int defer = (pmax[0] <= mrun[0] + 8.0f) && (pmax[1] <= mrun[1] + 8.0f);
        if (!__all(defer)) {
            float corr[2];
            #pragma unroll
            for (int nf = 0; nf < 2; ++nf) {
                float mnew = fmaxf(mrun[nf], pmax[nf]);
                corr[nf] = __builtin_amdgcn_exp2f(mrun[nf] - mnew);
                mrun[nf] = mnew;
            }
            #pragma unroll
            for (int qf = 0; qf < 2; ++qf)
                #pragma unroll
                for (int r = 0; r < 4; ++r) {
                    float c = __shfl(corr[qf], 4 * g + r);
                    lrun[qf][r] *= c;
                    #pragma unroll
                    for (int df = 0; df < 4; ++df) off[qf][df][r] *= c;
                }
        }
        #pragma unroll
        for (int nf = 0; nf < 2; ++nf) {
            const float nm = mrun[nf];
            #pragma unroll
            for (int mf = 0; mf < 4; ++mf)
                #pragma unroll
                for (int r = 0; r < 4; ++r)
                    sc[mf][nf][r] = __builtin_amdgcn_exp2f(sc[mf][nf][r] - nm);
        }

        // pack P -> bf16, write to wave-own rows of QPs
        #pragma unroll
        for (int nf = 0; nf < 2; ++nf) {
            int row = wq + nf * 16 + l15;
            #pragma unroll
            for (int mf = 0; mf < 4; ++mf) {
                unsigned p01, p23;
                asm("v_cvt_pk_bf16_f32 %0, %1, %2" : "=v"(p01) : "v"(sc[mf][nf][0]), "v"(sc[mf][nf][1]));
                asm("v_cvt_pk_bf16_f32 %0, %1, %2" : "=v"(p23) : "v"(sc[mf][nf][2]), "v"(sc[mf][nf][3]));
                uint2v pk = {p01, p23};
                int su = (mf * 2 + (g >> 1)) ^ (row & 7);
                *(uint2v*)&QPs[row * 64 + su * 8 + (g & 1) * 4] = pk;
            }
        }

        // ---- PV + row-sum MFMA ----
        f32x4 ts[2];
        ts[0] = (f32x4){0.f, 0.f, 0.f, 0.f};
        ts[1] = (f32x4){0.f, 0.f, 0.f, 0.f};
        __builtin_amdgcn_s_setprio(1);
        #pragma unroll
        for (int ki = 0; ki < 2; ++ki) {
            const int cu = ki * 4 + g;
            short8 pa[2], vb[4];
            #pragma unroll
            for (int qf = 0; qf < 2; ++qf) {
                int row = wq + qf * 16 + l15;
                pa[qf] = *(const short8*)&QPs[(row * 8 + (cu ^ (row & 7))) * 8];
            }
            #pragma unroll
            for (int df = 0; df < 4; ++df) {
                int d = df * 16 + l15;
                vb[df] = *(const short8*)&Vts[cur][(d * 8 + (cu ^ (d & 7))) * 8];
            }
            #pragma unroll
            for (int qf = 0; qf < 2; ++qf)
                #pragma unroll
                for (int df = 0; df < 4; ++df)
                    off[qf][df] = __builtin_amdgcn_mfma_f32_16x16x32_bf16(pa[qf], vb[df], off[qf][df], 0, 0, 0);
            #pragma unroll
            for (int qf = 0; qf < 2; ++qf)
                ts[qf] = __builtin_amdgcn_mfma_f32_16x16x32_bf16(pa[qf], ones, ts[qf], 0, 0, 0);
        }
        __builtin_amdgcn_s_setprio(0);
        #pragma unroll
        for (int qf = 0; qf < 2; ++qf)
            #pragma unroll
            for (int r = 0; r < 4; ++r) lrun[qf][r] += ts[qf][r];

        // ---- write next tile to buf[cur^1], then the one barrier ----
        if (kt + 1 < NT) {
            const int nxt = cur ^ 1;
            *(short8*)&Ks[nxt][lds0]  = kreg0;
            *(short8*)&Ks[nxt][lds1]  = kreg1;
            *(short8*)&Vts[nxt][lds0] = vreg0;
            *(short8*)&Vts[nxt][lds1] = vreg1;
        }
        __syncthreads();
    }

    // ---- normalize + store bf16 (all O-layout, no shfl) ----
    #pragma unroll
    for (int qf = 0; qf < 2; ++qf) {
        #pragma unroll
        for (int r = 0; r < 4; ++r) {
            const float inv = 1.0f / lrun[qf][r];
            const size_t row = rowbase + q0 + wq + qf * 16 + 4 * g + r;
            #pragma unroll
            for (int df = 0; df < 4; ++df) {
                float val = off[qf][df][r] * inv;
                ao[row * MD + h * 64 + df * 16 + l15] = f2b(val);
            }
        }
    }
}

// ---------------------------------------------------------------------------
// In-place LayerNorm over last dim (1024). One block per row, 256 threads.
// ---------------------------------------------------------------------------
__global__ __launch_bounds__(256)
void ln_kernel(float* __restrict__ X, const float* __restrict__ gamma,
               const float* __restrict__ beta)
{
    const int row = blockIdx.x;
    const int tid = threadIdx.x;
    float* px = X + (size_t)row * MD;
    f32x4 x = ((const f32x4*)px)[tid];
    float s  = x[0] + x[1] + x[2] + x[3];
    float ss = fmaf(x[0], x[0], fmaf(x[1], x[1], fmaf(x[2], x[2], x[3] * x[3])));
    #pragma unroll
    for (int off = 1; off < 64; off <<= 1) {
        s  += __shfl_xor(s,  off);
        ss += __shfl_xor(ss, off);
    }
    __shared__ float red[8];
    const int wid = tid >> 6;
    if ((tid & 63) == 0) { red[wid] = s; red[wid + 4] = ss; }
    __syncthreads();
    s  = red[0] + red[1] + red[2] + red[3];
    ss = red[4] + red[5] + red[6] + red[7];
    const float mu   = s * (1.0f / MD);
    const float var  = ss * (1.0f / MD) - mu * mu;
    const float rstd = rsqrtf(var + 1e-5f);
    f32x4 gm = ((const f32x4*)gamma)[tid];
    f32x4 be = ((const f32x4*)beta)[tid];
    f32x4 r;
    r[0] = (x[0] - mu) * rstd * gm[0] + be[0];
    r[1] = (x[1] - mu) * rstd * gm[1] + be[1];
    r[2] = (x[2] - mu) * rstd * gm[2] + be[2];
    r[3] = (x[3] - mu) * rstd * gm[3] + be[3];
    ((f32x4*)px)[tid] = r;
}

// ---------------------------------------------------------------------------
extern "C" void kernel_launch(void* const* d_in, const int* in_sizes, int n_in,
                              void* d_out, int out_size, void* d_ws, size_t ws_size,
                              hipStream_t stream)
{
    const float* query = (const float*)d_in[0];
    const float* key   = (const float*)d_in[1];
    const float* value = (const float*)d_in[2];
    const float* Wq = (const float*)d_in[3];
    const float* bq = (const float*)d_in[4];
    const float* Wk = (const float*)d_in[5];
    const float* bk = (const float*)d_in[6];
    const float* Wv = (const float*)d_in[7];
    const float* bv = (const float*)d_in[8];
    const float* Wo = (const float*)d_in[9];
    const float* bo = (const float*)d_in[10];
    const float* gamma = (const float*)d_in[11];
    const float* beta  = (const float*)d_in[12];
    float* out = (float*)d_out;

    const size_t NTOK = (size_t)BATCH * SEQ;            // 8192
    const size_t ACT  = NTOK * MD;                      // 8M elems

    unsigned short* qa  = (unsigned short*)d_ws;        // 16MB; later reused as vt
    unsigned short* ka  = qa + ACT;                     // 16MB; later reused as ao
    unsigned short* va  = ka + ACT;                     // 16MB
    unsigned short* WqT = va + ACT;                     // 2MB each
    unsigned short* WkT = WqT + (size_t)MD * MD;
    unsigned short* WvT = WkT + (size_t)MD * MD;
    unsigned short* WoT = WvT + (size_t)MD * MD;
    unsigned short* qp  = WoT + (size_t)MD * MD;        // 16MB
    unsigned short* kp  = qp + ACT;
    unsigned short* vp  = kp + ACT;
    unsigned short* vtb = qa;   // reuse (qa dead after Q-projection)
    unsigned short* ao  = ka;   // reuse (ka dead after K-projection)

    dim3 blk(256);

    prep_kernel<<<dim3(4096, 4), blk, 0, stream>>>(
        query, key, value, qa, ka, va, (int)ACT,
        Wq, Wk, Wv, Wo, WqT, WkT, WvT, WoT);

    dim3 gg(MD / 128, NTOK / 128, 3);   // (8, 64, 3) -> 1536 blocks
    gemm_qkv<<<gg, blk, 0, stream>>>(qa, ka, va, WqT, WkT, WvT,
                                     bq, bk, bv, qp, kp, vp);

    vtrans<<<dim3(SEQ / 64, 64), blk, 0, stream>>>(vp, vtb);

    attn_mfma<<<dim3(SEQ / 128, 64), blk, 0, stream>>>(qp, kp, vtb, ao);

    gemm_o<<<dim3(MD / 128, NTOK / 128), blk, 0, stream>>>(ao, WoT, bo, query, out);

    ln_kernel<<<NTOK, blk, 0, stream>>>(out, gamma, beta);
}

// Round 5
// 225.094 us; speedup vs baseline: 11.5109x; 1.1058x over previous
//
#include <hip/hip_runtime.h>
#include <math.h>

#define MD 1024
#define NH 16
#define HD 64
#define BATCH 4
#define SEQ 2048

typedef __attribute__((ext_vector_type(8))) short short8;
typedef __attribute__((ext_vector_type(4))) short short4v;
typedef __attribute__((ext_vector_type(4))) float f32x4;
typedef __attribute__((ext_vector_type(2))) unsigned int uint2v;

#define GLOAD16(gp, lp) __builtin_amdgcn_global_load_lds( \
    (const __attribute__((address_space(1))) void*)(gp),  \
    (__attribute__((address_space(3))) void*)(lp), 16, 0, 0)

__device__ inline unsigned short f2b(float f) {
    unsigned u = __builtin_bit_cast(unsigned, f);
    unsigned r = (u + 0x7fffu + ((u >> 16) & 1u)) >> 16;
    return (unsigned short)r;
}
__device__ inline float b2f(unsigned short s) {
    return __builtin_bit_cast(float, ((unsigned)s) << 16);
}

// ---------------------------------------------------------------------------
// Fused prep: y<3 -> fp32->bf16 convert of q/k/v activations;
//             y==3 -> W[K][N] fp32 -> WT[N][K] bf16 for all 4 weights.
// ---------------------------------------------------------------------------
__global__ __launch_bounds__(256)
void prep_kernel(const float* __restrict__ x0, const float* __restrict__ x1,
                 const float* __restrict__ x2, unsigned short* __restrict__ y0,
                 unsigned short* __restrict__ y1, unsigned short* __restrict__ y2,
                 int n,
                 const float* __restrict__ W0, const float* __restrict__ W1,
                 const float* __restrict__ W2, const float* __restrict__ W3,
                 unsigned short* __restrict__ T0, unsigned short* __restrict__ T1,
                 unsigned short* __restrict__ T2, unsigned short* __restrict__ T3)
{
    __shared__ __attribute__((aligned(16))) float T[64][68];
    const int tid = threadIdx.x;
    if (blockIdx.y < 3) {
        const float* x = (blockIdx.y == 0) ? x0 : (blockIdx.y == 1) ? x1 : x2;
        unsigned short* y = (blockIdx.y == 0) ? y0 : (blockIdx.y == 1) ? y1 : y2;
        int i = (blockIdx.x * 256 + tid) * 8;
        if (i >= n) return;
        f32x4 a = *(const f32x4*)(x + i);
        f32x4 b = *(const f32x4*)(x + i + 4);
        short8 o;
        o[0] = (short)f2b(a[0]); o[1] = (short)f2b(a[1]);
        o[2] = (short)f2b(a[2]); o[3] = (short)f2b(a[3]);
        o[4] = (short)f2b(b[0]); o[5] = (short)f2b(b[1]);
        o[6] = (short)f2b(b[2]); o[7] = (short)f2b(b[3]);
        *(short8*)(y + i) = o;
        return;
    }
    const int bx = blockIdx.x;
    if (bx >= 1024) return;
    const int z = bx >> 8, t = bx & 255;
    const int nt = t & 15, kt = t >> 4;
    const float* W = (z == 0) ? W0 : (z == 1) ? W1 : (z == 2) ? W2 : W3;
    unsigned short* WT = (z == 0) ? T0 : (z == 1) ? T1 : (z == 2) ? T2 : T3;
    #pragma unroll
    for (int i = 0; i < 4; ++i) {
        int u = tid + i * 256;
        int row = u >> 4, c4 = u & 15;
        f32x4 v = *(const f32x4*)(W + (size_t)(kt * 64 + row) * MD + nt * 64 + c4 * 4);
        *(f32x4*)&T[row][c4 * 4] = v;
    }
    __syncthreads();
    #pragma unroll
    for (int i = 0; i < 2; ++i) {
        int u = tid + i * 256;
        int nn = u >> 3, c16 = u & 7;
        short8 o;
        #pragma unroll
        for (int j = 0; j < 8; ++j) o[j] = (short)f2b(T[c16 * 8 + j][nn]);
        *(short8*)(WT + (size_t)(nt * 64 + nn) * MD + kt * 64 + c16 * 8) = o;
    }
}

// ---------------------------------------------------------------------------
// GEMM core: 128x128 tile, BK=64, global_load_lds width-16, XCD swizzle.
// Computes acc and tile origin; epilogue is caller's.
// ---------------------------------------------------------------------------
__device__ __forceinline__
void gemm_core(const unsigned short* __restrict__ A,
               const unsigned short* __restrict__ Bt,
               short* As, short* Bs, f32x4 acc[4][4],
               int* obrow, int* obcol)
{
    const int tid = threadIdx.x;
    const int lane = tid & 63;
    const int wave = tid >> 6;
    const int wm = wave >> 1, wn = wave & 1;
    const int l15 = lane & 15, g = lane >> 4;

    const int nbx = gridDim.x;
    const int bid = blockIdx.y * nbx + blockIdx.x;
    const int cpx = (nbx * gridDim.y) >> 3;
    const int swz = (bid & 7) * cpx + (bid >> 3);
    const int brow = (swz / nbx) * 128;
    const int bcol = (swz % nbx) * 128;
    *obrow = brow; *obcol = bcol;

    #pragma unroll
    for (int m = 0; m < 4; ++m)
        #pragma unroll
        for (int n = 0; n < 4; ++n) acc[m][n] = (f32x4){0.f, 0.f, 0.f, 0.f};

    for (int k0 = 0; k0 < MD; k0 += 64) {
        __syncthreads();
        #pragma unroll
        for (int i = 0; i < 4; ++i) {
            const int U = (i * 4 + wave) * 64 + lane;
            const int row = U >> 3, c16 = U & 7;
            GLOAD16(A  + (size_t)(brow + row) * MD + k0 + c16 * 8, &As[U * 8]);
            GLOAD16(Bt + (size_t)(bcol + row) * MD + k0 + c16 * 8, &Bs[U * 8]);
        }
        __syncthreads();
        #pragma unroll
        for (int kk = 0; kk < 64; kk += 32) {
            short8 af[4], bf_[4];
            #pragma unroll
            for (int m = 0; m < 4; ++m)
                af[m] = *(const short8*)&As[(wm * 64 + m * 16 + l15) * 64 + kk + g * 8];
            #pragma unroll
            for (int n = 0; n < 4; ++n)
                bf_[n] = *(const short8*)&Bs[(wn * 64 + n * 16 + l15) * 64 + kk + g * 8];
            #pragma unroll
            for (int m = 0; m < 4; ++m)
                #pragma unroll
                for (int n = 0; n < 4; ++n)
                    acc[m][n] = __builtin_amdgcn_mfma_f32_16x16x32_bf16(af[m], bf_[n], acc[m][n], 0, 0, 0);
        }
    }
}

// Q/K/V projections in one launch; blockIdx.z selects.
// z=0: Q -> bf16 scaled by 0.125*log2(e).  z=1: K -> bf16.
// z=2: V -> transposed bf16 vt[bh*64+d][s] (packed b64 stores).
__global__ __launch_bounds__(256, 2)
void gemm_qkv(const unsigned short* __restrict__ A0, const unsigned short* __restrict__ A1,
              const unsigned short* __restrict__ A2,
              const unsigned short* __restrict__ B0, const unsigned short* __restrict__ B1,
              const unsigned short* __restrict__ B2,
              const float* __restrict__ b0, const float* __restrict__ b1,
              const float* __restrict__ b2,
              unsigned short* __restrict__ Cq, unsigned short* __restrict__ Ck,
              unsigned short* __restrict__ Cvt)
{
    __shared__ __attribute__((aligned(16))) short As[128 * 64];
    __shared__ __attribute__((aligned(16))) short Bs[128 * 64];
    const int z = blockIdx.z;
    const unsigned short* A  = (z == 0) ? A0 : (z == 1) ? A1 : A2;
    const unsigned short* Bt = (z == 0) ? B0 : (z == 1) ? B1 : B2;
    const float* bias        = (z == 0) ? b0 : (z == 1) ? b1 : b2;

    f32x4 acc[4][4];
    int brow, bcol;
    gemm_core(A, Bt, As, Bs, acc, &brow, &bcol);

    const int tid = threadIdx.x;
    const int lane = tid & 63;
    const int wave = tid >> 6;
    const int wm = wave >> 1, wn = wave & 1;
    const int l15 = lane & 15, g = lane >> 4;

    if (z == 2) {
        // transposed V: vt[((b*16+h)*64+d)][s], 4 consecutive s packed
        #pragma unroll
        for (int m = 0; m < 4; ++m) {
            #pragma unroll
            for (int n = 0; n < 4; ++n) {
                const int col = bcol + wn * 64 + n * 16 + l15;
                const int h = col >> 6, d = col & 63;
                const float bv_ = bias[col];
                const int row0 = brow + wm * 64 + m * 16 + 4 * g;
                const int bb = row0 >> 11, s = row0 & 2047;
                short4v pk;
                #pragma unroll
                for (int r = 0; r < 4; ++r) pk[r] = (short)f2b(acc[m][n][r] + bv_);
                *(short4v*)(Cvt + ((size_t)((bb << 4) + h) * 64 + d) * SEQ + s) = pk;
            }
        }
        return;
    }
    const float scale = (z == 0) ? (0.125f * 1.44269504088896f) : 1.0f;
    unsigned short* C = (z == 0) ? Cq : Ck;
    #pragma unroll
    for (int m = 0; m < 4; ++m) {
        #pragma unroll
        for (int n = 0; n < 4; ++n) {
            const int col = bcol + wn * 64 + n * 16 + l15;
            const float bcol_v = bias[col];
            #pragma unroll
            for (int r = 0; r < 4; ++r) {
                const size_t row = (size_t)(brow + wm * 64 + m * 16 + 4 * g + r);
                C[row * MD + col] = f2b((acc[m][n][r] + bcol_v) * scale);
            }
        }
    }
}

// O-projection: fp32 out + bias + residual.
__global__ __launch_bounds__(256, 2)
void gemm_o(const unsigned short* __restrict__ A, const unsigned short* __restrict__ Bt,
            const float* __restrict__ bias, const float* __restrict__ residual,
            float* __restrict__ Cf)
{
    __shared__ __attribute__((aligned(16))) short As[128 * 64];
    __shared__ __attribute__((aligned(16))) short Bs[128 * 64];
    f32x4 acc[4][4];
    int brow, bcol;
    gemm_core(A, Bt, As, Bs, acc, &brow, &bcol);

    const int tid = threadIdx.x;
    const int lane = tid & 63;
    const int wave = tid >> 6;
    const int wm = wave >> 1, wn = wave & 1;
    const int l15 = lane & 15, g = lane >> 4;
    #pragma unroll
    for (int m = 0; m < 4; ++m) {
        #pragma unroll
        for (int n = 0; n < 4; ++n) {
            const int col = bcol + wn * 64 + n * 16 + l15;
            const float bcol_v = bias[col];
            #pragma unroll
            for (int r = 0; r < 4; ++r) {
                const size_t row = (size_t)(brow + wm * 64 + m * 16 + 4 * g + r);
                Cf[row * MD + col] = acc[m][n][r] + bcol_v + residual[row * MD + col];
            }
        }
    }
}

// ---------------------------------------------------------------------------
// Flash attention, bf16 MFMA. QBLK=256 (64 q-rows/wave), KV tile 64.
// Q direct global->reg (pre-scaled by Q-GEMM). Double-buffered K/V LDS,
// one barrier/tile. exp2-domain softmax, defer-max, row-sums via mfma(P,1).
// Grid (8, 64 bh), 256 thr = 4 waves. LDS = 32K P + 16K K + 16K V = 64KB.
// ---------------------------------------------------------------------------
__global__ __launch_bounds__(256, 2)
void attn_mfma(const unsigned short* __restrict__ qp,
               const unsigned short* __restrict__ kp,
               const unsigned short* __restrict__ vt,
               unsigned short* __restrict__ ao)
{
    __shared__ __attribute__((aligned(16))) short Ps[256 * 64];
    __shared__ __attribute__((aligned(16))) short Ks[2][64 * 64];
    __shared__ __attribute__((aligned(16))) short Vts[2][64 * 64];

    const int tid = threadIdx.x;
    const int lane = tid & 63;
    const int wave = tid >> 6;
    const int l15 = lane & 15, g = lane >> 4;
    const int qt = blockIdx.x, bh = blockIdx.y;
    const int b = bh >> 4, h = bh & 15;
    const size_t rowbase = (size_t)b * SEQ;
    const int q0 = qt * 256;
    const int wq = wave * 64;
    const int NT = SEQ / 64;

    // staging geometry (loop-invariant)
    const int r0 = tid >> 3, c16 = tid & 7;
    const int r1 = r0 + 32;
    const int lds0 = (r0 * 8 + (c16 ^ (r0 & 7))) * 8;
    const int lds1 = (r1 * 8 + (c16 ^ (r1 & 7))) * 8;
    const unsigned short* kbase = kp + (rowbase + r0) * MD + h * 64 + c16 * 8;
    const unsigned short* vbase = vt + ((size_t)bh * 64 + r0) * SEQ + c16 * 8;

    // ---- Q direct to registers (pre-scaled by Q-GEMM epilogue) ----
    short8 qreg[4][2];
    #pragma unroll
    for (int nf = 0; nf < 4; ++nf)
        #pragma unroll
        for (int ki = 0; ki < 2; ++ki)
            qreg[nf][ki] = *(const short8*)(qp + (rowbase + q0 + wq + nf * 16 + l15) * MD
                                               + h * 64 + ki * 32 + g * 8);

    // ---- stage KV tile 0 into buf 0 ----
    {
        short8 k0v = *(const short8*)(kbase);
        short8 k1v = *(const short8*)(kbase + 32 * MD);
        short8 v0v = *(const short8*)(vbase);
        short8 v1v = *(const short8*)(vbase + 32 * SEQ);
        *(short8*)&Ks[0][lds0]  = k0v;
        *(short8*)&Ks[0][lds1]  = k1v;
        *(short8*)&Vts[0][lds0] = v0v;
        *(short8*)&Vts[0][lds1] = v1v;
    }
    __syncthreads();

    short8 ones;
    #pragma unroll
    for (int j = 0; j < 8; ++j) ones[j] = (short)0x3F80;

    float mrun[4] = {-INFINITY, -INFINITY, -INFINITY, -INFINITY};
    f32x4 lrun[4];
    f32x4 off[4][4];
    #pragma unroll
    for (int qf = 0; qf < 4; ++qf) {
        lrun[qf] = (f32x4){0.f, 0.f, 0.f, 0.f};
        #pragma unroll
        for (int df = 0; df < 4; ++df) off[qf][df] = (f32x4){0.f, 0.f, 0.f, 0.f};
    }

    for (int kt = 0; kt < NT; ++kt) {
        const int cur = kt & 1;

        // prefetch next tile into regs
        short8 kreg0, kreg1, vreg0, vreg1;
        if (kt + 1 < NT) {
            const unsigned short* kb = kbase + (size_t)(kt + 1) * 64 * MD;
            const unsigned short* vb = vbase + (kt + 1) * 64;
            kreg0 = *(const short8*)(kb);
            kreg1 = *(const short8*)(kb + 32 * MD);
            vreg0 = *(const short8*)(vb);
            vreg1 = *(const short8*)(vb + 32 * SEQ);
        }

        // ---- S^T = K @ Q^T ----
        f32x4 sc[4][4];
        #pragma unroll
        for (int mf = 0; mf < 4; ++mf)
            #pragma unroll
            for (int nf = 0; nf < 4; ++nf) sc[mf][nf] = (f32x4){0.f, 0.f, 0.f, 0.f};
        __builtin_amdgcn_s_setprio(1);
        #pragma unroll
        for (int ki = 0; ki < 2; ++ki) {
            const int cu = ki * 4 + g;
            short8 af[4];
            #pragma unroll
            for (int mf = 0; mf < 4; ++mf) {
                int row = mf * 16 + l15;
                af[mf] = *(const short8*)&Ks[cur][(row * 8 + (cu ^ (row & 7))) * 8];
            }
            #pragma unroll
            for (int mf = 0; mf < 4; ++mf)
                #pragma unroll
                for (int nf = 0; nf < 4; ++nf)
                    sc[mf][nf] = __builtin_amdgcn_mfma_f32_16x16x32_bf16(af[mf], qreg[nf][ki], sc[mf][nf], 0, 0, 0);
        }
        __builtin_amdgcn_s_setprio(0);

        // ---- online softmax (log2 domain), defer-max THR=8 ----
        float pmax[4];
        #pragma unroll
        for (int nf = 0; nf < 4; ++nf) {
            float pm = -INFINITY;
            #pragma unroll
            for (int mf = 0; mf < 4; ++mf)
                #pragma unroll
                for (int r = 0; r < 4; ++r) pm = fmaxf(pm, sc[mf][nf][r]);
            pm = fmaxf(pm, __shfl_xor(pm, 16));
            pm = fmaxf(pm, __shfl_xor(pm, 32));
            pmax[nf] = pm;
        }
        const int defer = (pmax[0] <= mrun[0] + 8.0f) && (pmax[1] <= mrun[1] + 8.0f) &&
                          (pmax[2] <= mrun[2] + 8.0f) && (pmax[3] <= mrun[3] + 8.0f);
        if (!__all(defer)) {
            float corr[4];
            #pragma unroll
            for (int nf = 0; nf < 4; ++nf) {
                float mnew = fmaxf(mrun[nf], pmax[nf]);
                corr[nf] = __builtin_amdgcn_exp2f(mrun[nf] - mnew);
                mrun[nf] = mnew;
            }
            #pragma unroll
            for (int qf = 0; qf < 4; ++qf)
                #pragma unroll
                for (int r = 0; r < 4; ++r) {
                    float c = __shfl(corr[qf], 4 * g + r);
                    lrun[qf][r] *= c;
                    #pragma unroll
                    for (int df = 0; df < 4; ++df) off[qf][df][r] *= c;
                }
        }
        #pragma unroll
        for (int nf = 0; nf < 4; ++nf) {
            const float nm = mrun[nf];
            #pragma unroll
            for (int mf = 0; mf < 4; ++mf)
                #pragma unroll
                for (int r = 0; r < 4; ++r)
                    sc[mf][nf][r] = __builtin_amdgcn_exp2f(sc[mf][nf][r] - nm);
        }

        // ---- pack P -> bf16, wave-own rows of Ps ----
        #pragma unroll
        for (int nf = 0; nf < 4; ++nf) {
            int row = wq + nf * 16 + l15;
            #pragma unroll
            for (int mf = 0; mf < 4; ++mf) {
                unsigned p01, p23;
                asm("v_cvt_pk_bf16_f32 %0, %1, %2" : "=v"(p01) : "v"(sc[mf][nf][0]), "v"(sc[mf][nf][1]));
                asm("v_cvt_pk_bf16_f32 %0, %1, %2" : "=v"(p23) : "v"(sc[mf][nf][2]), "v"(sc[mf][nf][3]));
                uint2v pk = {p01, p23};
                int su = (mf * 2 + (g >> 1)) ^ (row & 7);
                *(uint2v*)&Ps[row * 64 + su * 8 + (g & 1) * 4] = pk;
            }
        }

        // ---- PV + row-sum MFMA ----
        f32x4 ts[4];
        #pragma unroll
        for (int qf = 0; qf < 4; ++qf) ts[qf] = (f32x4){0.f, 0.f, 0.f, 0.f};
        __builtin_amdgcn_s_setprio(1);
        #pragma unroll
        for (int ki = 0; ki < 2; ++ki) {
            const int cu = ki * 4 + g;
            short8 pa[4], vb[4];
            #pragma unroll
            for (int qf = 0; qf < 4; ++qf) {
                int row = wq + qf * 16 + l15;
                pa[qf] = *(const short8*)&Ps[(row * 8 + (cu ^ (row & 7))) * 8];
            }
            #pragma unroll
            for (int df = 0; df < 4; ++df) {
                int d = df * 16 + l15;
                vb[df] = *(const short8*)&Vts[cur][(d * 8 + (cu ^ (d & 7))) * 8];
            }
            #pragma unroll
            for (int qf = 0; qf < 4; ++qf)
                #pragma unroll
                for (int df = 0; df < 4; ++df)
                    off[qf][df] = __builtin_amdgcn_mfma_f32_16x16x32_bf16(pa[qf], vb[df], off[qf][df], 0, 0, 0);
            #pragma unroll
            for (int qf = 0; qf < 4; ++qf)
                ts[qf] = __builtin_amdgcn_mfma_f32_16x16x32_bf16(pa[qf], ones, ts[qf], 0, 0, 0);
        }
        __builtin_amdgcn_s_setprio(0);
        #pragma unroll
        for (int qf = 0; qf < 4; ++qf)
            #pragma unroll
            for (int r = 0; r < 4; ++r) lrun[qf][r] += ts[qf][r];

        // ---- write next tile to buf[cur^1], then the one barrier ----
        if (kt + 1 < NT) {
            const int nxt = cur ^ 1;
            *(short8*)&Ks[nxt][lds0]  = kreg0;
            *(short8*)&Ks[nxt][lds1]  = kreg1;
            *(short8*)&Vts[nxt][lds0] = vreg0;
            *(short8*)&Vts[nxt][lds1] = vreg1;
        }
        __syncthreads();
    }

    // ---- normalize + store bf16 ----
    #pragma unroll
    for (int qf = 0; qf < 4; ++qf) {
        #pragma unroll
        for (int r = 0; r < 4; ++r) {
            const float inv = 1.0f / lrun[qf][r];
            const size_t row = rowbase + q0 + wq + qf * 16 + 4 * g + r;
            #pragma unroll
            for (int df = 0; df < 4; ++df) {
                float val = off[qf][df][r] * inv;
                ao[row * MD + h * 64 + df * 16 + l15] = f2b(val);
            }
        }
    }
}

// ---------------------------------------------------------------------------
// In-place LayerNorm over last dim (1024). One block per row, 256 threads.
// ---------------------------------------------------------------------------
__global__ __launch_bounds__(256)
void ln_kernel(float* __restrict__ X, const float* __restrict__ gamma,
               const float* __restrict__ beta)
{
    const int row = blockIdx.x;
    const int tid = threadIdx.x;
    float* px = X + (size_t)row * MD;
    f32x4 x = ((const f32x4*)px)[tid];
    float s  = x[0] + x[1] + x[2] + x[3];
    float ss = fmaf(x[0], x[0], fmaf(x[1], x[1], fmaf(x[2], x[2], x[3] * x[3])));
    #pragma unroll
    for (int off = 1; off < 64; off <<= 1) {
        s  += __shfl_xor(s,  off);
        ss += __shfl_xor(ss, off);
    }
    __shared__ float red[8];
    const int wid = tid >> 6;
    if ((tid & 63) == 0) { red[wid] = s; red[wid + 4] = ss; }
    __syncthreads();
    s  = red[0] + red[1] + red[2] + red[3];
    ss = red[4] + red[5] + red[6] + red[7];
    const float mu   = s * (1.0f / MD);
    const float var  = ss * (1.0f / MD) - mu * mu;
    const float rstd = rsqrtf(var + 1e-5f);
    f32x4 gm = ((const f32x4*)gamma)[tid];
    f32x4 be = ((const f32x4*)beta)[tid];
    f32x4 r;
    r[0] = (x[0] - mu) * rstd * gm[0] + be[0];
    r[1] = (x[1] - mu) * rstd * gm[1] + be[1];
    r[2] = (x[2] - mu) * rstd * gm[2] + be[2];
    r[3] = (x[3] - mu) * rstd * gm[3] + be[3];
    ((f32x4*)px)[tid] = r;
}

// ---------------------------------------------------------------------------
extern "C" void kernel_launch(void* const* d_in, const int* in_sizes, int n_in,
                              void* d_out, int out_size, void* d_ws, size_t ws_size,
                              hipStream_t stream)
{
    const float* query = (const float*)d_in[0];
    const float* key   = (const float*)d_in[1];
    const float* value = (const float*)d_in[2];
    const float* Wq = (const float*)d_in[3];
    const float* bq = (const float*)d_in[4];
    const float* Wk = (const float*)d_in[5];
    const float* bk = (const float*)d_in[6];
    const float* Wv = (const float*)d_in[7];
    const float* bv = (const float*)d_in[8];
    const float* Wo = (const float*)d_in[9];
    const float* bo = (const float*)d_in[10];
    const float* gamma = (const float*)d_in[11];
    const float* beta  = (const float*)d_in[12];
    float* out = (float*)d_out;

    const size_t NTOK = (size_t)BATCH * SEQ;            // 8192
    const size_t ACT  = NTOK * MD;                      // 8M elems

    unsigned short* qa  = (unsigned short*)d_ws;        // bf16 query act
    unsigned short* ka  = qa + ACT;                     // bf16 key act; later ao
    unsigned short* va  = ka + ACT;                     // bf16 value act
    unsigned short* WqT = va + ACT;
    unsigned short* WkT = WqT + (size_t)MD * MD;
    unsigned short* WvT = WkT + (size_t)MD * MD;
    unsigned short* WoT = WvT + (size_t)MD * MD;
    unsigned short* qp  = WoT + (size_t)MD * MD;        // Q proj (pre-scaled)
    unsigned short* kp  = qp + ACT;                     // K proj
    unsigned short* vtp = kp + ACT;                     // V proj, transposed [bh*64+d][s]
    unsigned short* ao  = ka;   // reuse (ka dead after K-projection)

    dim3 blk(256);

    prep_kernel<<<dim3(4096, 4), blk, 0, stream>>>(
        query, key, value, qa, ka, va, (int)ACT,
        Wq, Wk, Wv, Wo, WqT, WkT, WvT, WoT);

    dim3 gg(MD / 128, NTOK / 128, 3);   // (8, 64, 3)
    gemm_qkv<<<gg, blk, 0, stream>>>(qa, ka, va, WqT, WkT, WvT,
                                     bq, bk, bv, qp, kp, vtp);

    attn_mfma<<<dim3(SEQ / 256, 64), blk, 0, stream>>>(qp, kp, vtp, ao);

    gemm_o<<<dim3(MD / 128, NTOK / 128), blk, 0, stream>>>(ao, WoT, bo, query, out);

    ln_kernel<<<NTOK, blk, 0, stream>>>(out, gamma, beta);
}